// Round 15
// baseline (178.384 us; speedup 1.0000x reference)
//
#include <hip/hip_runtime.h>
#include <hip/hip_bf16.h>
#include <stdint.h>

typedef __hip_bfloat16 bf16;
typedef __attribute__((ext_vector_type(4))) short short4v;
typedef __attribute__((ext_vector_type(8))) short short8v;
typedef __attribute__((ext_vector_type(4))) float f32x4;

#define MFMA16(a,b,c) __builtin_amdgcn_mfma_f32_16x16x32_bf16(a,b,c,0,0,0)
#define SCALE2 0.18033688011f   /* (1/sqrt(64)) * log2(e) — folded into Qb */

__device__ __forceinline__ void gload16(const void* g, void* l) {
  __builtin_amdgcn_global_load_lds((const __attribute__((address_space(1))) unsigned int*)g,
                                   (__attribute__((address_space(3))) unsigned int*)l, 16, 0, 0);
}

__device__ __forceinline__ short f2bs(float f) {
  return __builtin_bit_cast(short, __float2bfloat16(f));
}

__device__ __forceinline__ float max3f(float a, float b, float c) {
  return fmaxf(fmaxf(a, b), c);      // clang fuses to v_max3_f32 (T17)
}

// K-dim permutation within each 32-group: lane-group g's MFMA fragment
// {4g..4g+3, 16+4g..16+4g+3} becomes 8 CONTIGUOUS elements at 8g..8g+7.
// p(k) = ((k&15)>>2)*8 + ((k>>4)&1)*4 + (k&3)
// Applied to GEMM K-dims (xb/W*/attnb), attn d-dim (Qb/Kb), attn kv-dim (Vt cols).

// ---------------- merged prelude: cvt_x (permuted) + 4 transpose_cvt (permuted) ----------------
__global__ __launch_bounds__(256) void k_prep(const float* __restrict__ x,
    const float* __restrict__ Wq, const float* __restrict__ Wk,
    const float* __restrict__ Wv, const float* __restrict__ Wo,
    bf16* __restrict__ xb, bf16* __restrict__ WqT, bf16* __restrict__ WkT,
    bf16* __restrict__ WvT, bf16* __restrict__ WoT) {
  __shared__ float ts[64][65];
  const int bid = blockIdx.x;
  const int t = threadIdx.x;
  if (bid < 4096) {
    int f = (bid*256 + t)*4;
    int row = f >> 11, c = f & 2047;
    float4 v = *(const float4*)(x + (size_t)row*2048 + c);
    int pc = (c & ~31) | (((c & 15) >> 2) << 3) | (((c >> 4) & 1) << 2);
    short4v o;
    o[0] = f2bs(v.x); o[1] = f2bs(v.y); o[2] = f2bs(v.z); o[3] = f2bs(v.w);
    *(short4v*)(xb + (size_t)row*2048 + pc) = o;
    return;
  }
  int tb = bid - 4096;
  const float* W; bf16* Wt; int K, N, bx, by;
  if (tb < 1024)      { W = Wq; Wt = WqT; K = 2048; N = 2048; bx = tb & 31;         by = tb >> 5; }
  else if (tb < 1280) { W = Wk; Wt = WkT; K = 2048; N = 512;  bx = (tb-1024) & 7;   by = (tb-1024) >> 3; }
  else if (tb < 1536) { W = Wv; Wt = WvT; K = 2048; N = 512;  bx = (tb-1280) & 7;   by = (tb-1280) >> 3; }
  else                { W = Wo; Wt = WoT; K = 2048; N = 2048; bx = (tb-1536) & 31;  by = (tb-1536) >> 5; }
  const int k0 = by*64, n0 = bx*64;
  #pragma unroll
  for (int ii = 0; ii < 16; ++ii) {
    int idx = ii*256 + t; int r = idx>>6, c = idx&63;
    ts[r][c] = W[(size_t)(k0+r)*N + n0 + c];
  }
  __syncthreads();
  #pragma unroll
  for (int ii = 0; ii < 16; ++ii) {
    int idx = ii*256 + t; int r = idx>>6, c = idx&63;   // r: n-row, c: k-col (logical)
    int pc = (c & 32) | (((c & 15) >> 2) << 3) | (((c >> 4) & 1) << 2) | (c & 3);
    Wt[(size_t)(n0+r)*K + k0 + pc] = __float2bfloat16(ts[c][r]);
  }
}

// ---------------- QKV GEMM, FUSED RMSNorm+RoPE epilogue, b128 frags ----------------
// Q-heads additionally scaled by SCALE2. Q/K written d-PERMUTED; V written
// DIRECTLY TRANSPOSED into Vt [kv][64 d][2048 s-perm] (vtrans kernel eliminated).
__global__ __launch_bounds__(256) void k_gemm_qkv(const bf16* __restrict__ A, const bf16* __restrict__ Bt,
                                                  const float* __restrict__ cosb, const float* __restrict__ sinb,
                                                  const float* __restrict__ qg, const float* __restrict__ kg,
                                                  bf16* __restrict__ Qb, bf16* __restrict__ Kb,
                                                  bf16* __restrict__ Vt, int K) {
  __shared__ bf16 Asm[3][128*32];
  __shared__ bf16 Bsm[3][128*32];
  const int t = threadIdx.x;
  const int lane = t & 63, w = t >> 6;
  const int wr = w >> 1, wc = w & 1;
  const int m0 = blockIdx.y*128, n0 = blockIdx.x*128;
  const int l15 = lane & 15;
  const int g16 = (lane >> 4) << 4;

  f32x4 acc[4][4];
  #pragma unroll
  for (int i = 0; i < 4; ++i)
    #pragma unroll
    for (int j = 0; j < 4; ++j) acc[i][j] = 0.f;

  const char* Ab = (const char*)A;
  const char* Bb = (const char*)Bt;
  const int off  = t*16;
  const int srow = off >> 6;
  const int scolb = (((off >> 4) & 3) ^ ((srow >> 1) & 3)) << 4;

  const size_t arow0 = (size_t)(m0+srow)*K, arow1 = (size_t)(m0+srow+64)*K;
  const size_t brow0 = (size_t)(n0+srow)*K, brow1 = (size_t)(n0+srow+64)*K;

#define STAGE(buf, kk)  do {                                          \
    gload16(Ab + (arow0 + (kk))*2 + scolb, (char*)Asm[buf] + off);    \
    gload16(Ab + (arow1 + (kk))*2 + scolb, (char*)Asm[buf] + off + 4096); \
    gload16(Bb + (brow0 + (kk))*2 + scolb, (char*)Bsm[buf] + off);    \
    gload16(Bb + (brow1 + (kk))*2 + scolb, (char*)Bsm[buf] + off + 4096); \
  } while (0)

  const int nsteps = K >> 5;
  STAGE(0, 0);
  STAGE(1, 32);

  for (int it = 0; it < nsteps; ++it) {
    const int kf = (it + 2) << 5;
    if (kf < K) {
      STAGE((it + 2) % 3, kf);
      asm volatile("s_waitcnt vmcnt(8)" ::: "memory");
    } else if (it + 1 < nsteps) {
      asm volatile("s_waitcnt vmcnt(4)" ::: "memory");
    } else {
      asm volatile("s_waitcnt vmcnt(0)" ::: "memory");
    }
    __builtin_amdgcn_s_barrier();
    __builtin_amdgcn_sched_barrier(0);

    const char* Ac = (const char*)Asm[it % 3];
    const char* Bc = (const char*)Bsm[it % 3];
    short8v a[4], b[4];
    #pragma unroll
    for (int i = 0; i < 4; ++i) {
      const int arow = wr*64 + i*16 + l15;
      a[i] = *(const short8v*)(Ac + arow*64 + (g16 ^ (((arow >> 1) & 3) << 4)));
      const int brow = wc*64 + i*16 + l15;
      b[i] = *(const short8v*)(Bc + brow*64 + (g16 ^ (((brow >> 1) & 3) << 4)));
    }
    #pragma unroll
    for (int i = 0; i < 4; ++i)
      #pragma unroll
      for (int j = 0; j < 4; ++j)
        acc[i][j] = MFMA16(a[i], b[j], acc[i][j]);
    __builtin_amdgcn_sched_barrier(0);
    __builtin_amdgcn_s_barrier();
  }
#undef STAGE

  // ---- fused epilogue ----
  const int hh = (n0 + wc*64) >> 6;            // head id 0..47 (wave-uniform)
  if (hh < 40) {
    // rmsnorm + rope, d-PERMUTED store
    float gam[4];
    const float* gp = (hh < 32) ? qg : kg;
    #pragma unroll
    for (int j = 0; j < 4; ++j) gam[j] = gp[j*16 + l15];
    if (hh < 32) {
      #pragma unroll
      for (int j = 0; j < 4; ++j) gam[j] *= SCALE2;   // fold softmax scale into Q
    }
    const int pbase = ((l15 >> 2) << 3) + (l15 & 3);   // d-perm base for this lane
    #pragma unroll
    for (int i = 0; i < 4; ++i) {
      #pragma unroll
      for (int rr = 0; rr < 4; ++rr) {
        const int row = m0 + wr*64 + i*16 + ((lane>>4)<<2) + rr;   // absolute s
        float v0 = acc[i][0][rr], v1 = acc[i][1][rr], v2 = acc[i][2][rr], v3 = acc[i][3][rr];
        float ss = v0*v0 + v1*v1 + v2*v2 + v3*v3;
        ss += __shfl_xor(ss, 1); ss += __shfl_xor(ss, 2);
        ss += __shfl_xor(ss, 4); ss += __shfl_xor(ss, 8);
        const float rms = rsqrtf(ss*(1.0f/64.0f) + 1e-6f);
        const float t0 = v0*rms*gam[0], t1 = v1*rms*gam[1];
        const float t2 = v2*rms*gam[2], t3 = v3*rms*gam[3];
        const float* cr = cosb + (size_t)row*64;
        const float* sr = sinb + (size_t)row*64;
        const float o0 = t0*cr[l15]      - t2*sr[l15];
        const float o1 = t1*cr[16+l15]   - t3*sr[16+l15];
        const float o2 = t2*cr[32+l15]   + t0*sr[32+l15];
        const float o3 = t3*cr[48+l15]   + t1*sr[48+l15];
        bf16* dst = (hh < 32) ? (Qb + ((size_t)hh*2048 + row)*64)
                              : (Kb + ((size_t)(hh-32)*2048 + row)*64);
        dst[pbase]          = __float2bfloat16(o0);
        dst[pbase + 4]      = __float2bfloat16(o1);
        dst[32 + pbase]     = __float2bfloat16(o2);
        dst[32 + pbase + 4] = __float2bfloat16(o3);
      }
    }
  } else {
    // V: direct transposed store into Vt [kv][d][s-perm]; the 4 rr-values of
    // each (i,j) form one contiguous permuted quad -> short4v store.
    bf16* dstT = Vt + (size_t)(hh-40)*64*2048;
    #pragma unroll
    for (int i = 0; i < 4; ++i) {
      const int s_log = m0 + wr*64 + i*16 + ((lane>>4)<<2);   // 4-aligned quad base
      const int a_  = (s_log >> 2) & 7;                        // quad idx in 32-group
      const int ps  = (s_log & ~31) + ((a_ & 3) << 3) + ((a_ >> 2) << 2);
      #pragma unroll
      for (int j = 0; j < 4; ++j) {
        const int d = j*16 + l15;
        short4v vv;
        vv[0] = f2bs(acc[i][j][0]); vv[1] = f2bs(acc[i][j][1]);
        vv[2] = f2bs(acc[i][j][2]); vv[3] = f2bs(acc[i][j][3]);
        *(short4v*)(dstT + (size_t)d*2048 + ps) = vv;
      }
    }
  }
}

// ---------------- out-proj GEMM: direct f32 store, b128 frags, depth-2 prefetch ----------------
__global__ __launch_bounds__(256) void k_gemm_out(const bf16* __restrict__ A, const bf16* __restrict__ Bt,
                                                  float* __restrict__ C, int M, int N, int K, int ldc) {
  __shared__ bf16 Asm[3][128*32];
  __shared__ bf16 Bsm[3][128*32];
  const int t = threadIdx.x;
  const int lane = t & 63, w = t >> 6;
  const int wr = w >> 1, wc = w & 1;
  const int m0 = blockIdx.y*128, n0 = blockIdx.x*128;
  const int l15 = lane & 15;
  const int g16 = (lane >> 4) << 4;

  f32x4 acc[4][4];
  #pragma unroll
  for (int i = 0; i < 4; ++i)
    #pragma unroll
    for (int j = 0; j < 4; ++j) acc[i][j] = 0.f;

  const char* Ab = (const char*)A;
  const char* Bb = (const char*)Bt;
  const int off  = t*16;
  const int srow = off >> 6;
  const int scolb = (((off >> 4) & 3) ^ ((srow >> 1) & 3)) << 4;

  const size_t arow0 = (size_t)(m0+srow)*K, arow1 = (size_t)(m0+srow+64)*K;
  const size_t brow0 = (size_t)(n0+srow)*K, brow1 = (size_t)(n0+srow+64)*K;

#define STAGE(buf, kk)  do {                                          \
    gload16(Ab + (arow0 + (kk))*2 + scolb, (char*)Asm[buf] + off);    \
    gload16(Ab + (arow1 + (kk))*2 + scolb, (char*)Asm[buf] + off + 4096); \
    gload16(Bb + (brow0 + (kk))*2 + scolb, (char*)Bsm[buf] + off);    \
    gload16(Bb + (brow1 + (kk))*2 + scolb, (char*)Bsm[buf] + off + 4096); \
  } while (0)

  const int nsteps = K >> 5;
  STAGE(0, 0);
  STAGE(1, 32);

  for (int it = 0; it < nsteps; ++it) {
    if (it + 2 < nsteps) {
      STAGE((it + 2) % 3, (it + 2) << 5);
      asm volatile("s_waitcnt vmcnt(8)" ::: "memory");
    } else if (it + 1 < nsteps) {
      asm volatile("s_waitcnt vmcnt(4)" ::: "memory");
    } else {
      asm volatile("s_waitcnt vmcnt(0)" ::: "memory");
    }
    __builtin_amdgcn_s_barrier();
    __builtin_amdgcn_sched_barrier(0);

    const char* Ac = (const char*)Asm[it % 3];
    const char* Bc = (const char*)Bsm[it % 3];
    short8v a[4], b[4];
    #pragma unroll
    for (int i = 0; i < 4; ++i) {
      const int arow = wr*64 + i*16 + l15;
      a[i] = *(const short8v*)(Ac + arow*64 + (g16 ^ (((arow >> 1) & 3) << 4)));
      const int brow = wc*64 + i*16 + l15;
      b[i] = *(const short8v*)(Bc + brow*64 + (g16 ^ (((brow >> 1) & 3) << 4)));
    }
    #pragma unroll
    for (int i = 0; i < 4; ++i)
      #pragma unroll
      for (int j = 0; j < 4; ++j)
        acc[i][j] = MFMA16(a[i], b[j], acc[i][j]);
    __builtin_amdgcn_sched_barrier(0);
    __builtin_amdgcn_s_barrier();
  }
#undef STAGE

  #pragma unroll
  for (int i = 0; i < 4; ++i) {
    int row0 = m0 + wr*64 + i*16 + ((lane>>4)<<2);
    #pragma unroll
    for (int j = 0; j < 4; ++j) {
      int col = n0 + wc*64 + j*16 + l15;
      #pragma unroll
      for (int r = 0; r < 4; ++r)
        C[(size_t)(row0+r)*ldc + col] = acc[i][j][r];
    }
  }
}

// ---------------- causal flash attention v7: b128 frags + T14 async reg-staging ----------------
// Tile t held in regs; written to LDS at iter top; t+1's global loads issued
// right after the visibility barrier so HBM latency hides under QK^T+softmax+PV.
__global__ __launch_bounds__(512) void k_attn(const bf16* __restrict__ Qb, const bf16* __restrict__ Kb,
                                              const bf16* __restrict__ Vt, bf16* __restrict__ attnb) {
  __shared__ bf16 Ksm[128][72];   // stride 144 B: 16-aligned, 2-way banks (free)
  __shared__ bf16 Vsm[64][136];   // stride 272 B: 16-aligned, 2-way banks (free)
  const int t = threadIdx.x, lane = t & 63, w = t >> 6;
  const int bid = blockIdx.x;
  const int h = bid & 31;
  const int qi = 15 - (bid >> 5);          // heavy blocks first
  const int qb0 = qi * 128;
  const int kvh = h >> 2;
  const int kb = (lane>>4)*4;
  const int kb2 = kb << 1;                 // permuted-contiguous frag base (8g)
  const int l15 = lane & 15;

  const bf16* Qh = Qb + (size_t)h*2048*64;
  const bf16* Kh = Kb + (size_t)kvh*2048*64;
  const bf16* Vh = Vt + (size_t)kvh*64*2048;

  const int qrow = qb0 + w*16 + l15;       // this lane's q-row (replicated x4 groups)
  short8v qf[2];
  #pragma unroll
  for (int kk = 0; kk < 2; ++kk)
    qf[kk] = *(const short8v*)(Qh + (size_t)qrow*64 + kk*32 + kb2);

  float m_ = -3e38f, ls = 0.f;
  f32x4 o2[4];
  #pragma unroll
  for (int j = 0; j < 4; ++j) o2[j] = 0.f;

  // T14 staging state: tile 0 loaded in prologue
  int kr[2], kc[2], vr[2], vc[2];
  int4 kreg[2], vreg[2];
  #pragma unroll
  for (int ii = 0; ii < 2; ++ii) {
    int idx = ii*512 + t;
    kr[ii] = idx >> 3; kc[ii] = (idx & 7)*8;
    vr[ii] = idx >> 4; vc[ii] = (idx & 15)*8;
    kreg[ii] = *(const int4*)(Kh + ((size_t)kr[ii])*64 + kc[ii]);
    vreg[ii] = *(const int4*)(Vh + (size_t)vr[ii]*2048 + vc[ii]);
  }

  const int nt = qi + 1;
  for (int tt = 0; tt < nt; ++tt) {
    // write staged tile to LDS (prev iter's reads protected by end-of-iter barrier)
    #pragma unroll
    for (int ii = 0; ii < 2; ++ii) {
      *(int4*)(&Ksm[kr[ii]][kc[ii]]) = kreg[ii];
      *(int4*)(&Vsm[vr[ii]][vc[ii]]) = vreg[ii];
    }
    __syncthreads();

    // issue NEXT tile's loads now — latency hides under QK^T + softmax + PV
    if (tt + 1 < nt) {
      #pragma unroll
      for (int ii = 0; ii < 2; ++ii) {
        kreg[ii] = *(const int4*)(Kh + ((size_t)((tt+1)*128 + kr[ii]))*64 + kc[ii]);
        vreg[ii] = *(const int4*)(Vh + (size_t)vr[ii]*2048 + (tt+1)*128 + vc[ii]);
      }
    }

    // S^T = K Q^T -> sAcc[j]: kv-block j (0..7), q = l15 (pre-scaled via Q)
    f32x4 sAcc[8];
    #pragma unroll
    for (int j = 0; j < 8; ++j) sAcc[j] = 0.f;
    __builtin_amdgcn_s_setprio(1);
    #pragma unroll
    for (int kk = 0; kk < 2; ++kk) {
      #pragma unroll
      for (int j = 0; j < 8; ++j) {
        short8v ak = *(const short8v*)(&Ksm[j*16 + l15][kk*32 + kb2]);
        sAcc[j] = MFMA16(ak, qf[kk], sAcc[j]);
      }
    }
    __builtin_amdgcn_s_setprio(0);

    float p[8][4];
    #pragma unroll
    for (int j = 0; j < 8; ++j)
      #pragma unroll
      for (int r = 0; r < 4; ++r) p[j][r] = sAcc[j][r];
    if (tt == nt - 1) {                      // diagonal tile: causal mask
      #pragma unroll
      for (int j = 0; j < 8; ++j) {
        #pragma unroll
        for (int r = 0; r < 4; ++r)
          if (tt*128 + j*16 + kb + r > qrow) p[j][r] = -3e38f;
      }
    }

    // row max: max3 tree + cross-group combine
    float mj[8];
    #pragma unroll
    for (int j = 0; j < 8; ++j)
      mj[j] = fmaxf(max3f(p[j][0], p[j][1], p[j][2]), p[j][3]);
    float mx = fmaxf(max3f(mj[0], mj[1], mj[2]), max3f(mj[3], mj[4], mj[5]));
    mx = max3f(mx, mj[6], mj[7]);
    mx = fmaxf(mx, __shfl_xor(mx, 16));
    mx = fmaxf(mx, __shfl_xor(mx, 32));

    // defer-max (T13): skip rescale when tile max within 8 of running max
    float mn = m_;
    if (!__all(mx <= m_ + 8.f)) {
      mn = fmaxf(m_, mx);
      float alpha = exp2f(m_ - mn);
      m_ = mn;
      ls *= alpha;
      #pragma unroll
      for (int j = 0; j < 4; ++j) o2[j] *= alpha;
    }

    float rs = 0.f;
    #pragma unroll
    for (int j = 0; j < 8; ++j)
      #pragma unroll
      for (int r = 0; r < 4; ++r) {
        float e = exp2f(p[j][r] - mn);
        p[j][r] = e;
        rs += e;
      }
    rs += __shfl_xor(rs, 16);
    rs += __shfl_xor(rs, 32);
    ls += rs;

    short8v pb[4];
    #pragma unroll
    for (int kk = 0; kk < 4; ++kk) {
      short8v v;
      v[0] = f2bs(p[2*kk][0]);   v[1] = f2bs(p[2*kk][1]);
      v[2] = f2bs(p[2*kk][2]);   v[3] = f2bs(p[2*kk][3]);
      v[4] = f2bs(p[2*kk+1][0]); v[5] = f2bs(p[2*kk+1][1]);
      v[6] = f2bs(p[2*kk+1][2]); v[7] = f2bs(p[2*kk+1][3]);
      pb[kk] = v;
    }

    // O^T += V^T P -> o2[j]: d-block j, q = l15 (V kv-permuted -> b128 frags)
    __builtin_amdgcn_s_setprio(1);
    #pragma unroll
    for (int kk = 0; kk < 4; ++kk) {
      #pragma unroll
      for (int j = 0; j < 4; ++j) {
        short8v av = *(const short8v*)(&Vsm[j*16 + l15][kk*32 + kb2]);
        o2[j] = MFMA16(av, pb[kk], o2[j]);
      }
    }
    __builtin_amdgcn_s_setprio(0);
    __syncthreads();
  }

  // write attnb in K-PERMUTED layout (out-proj A-operand)
  float inv = 1.0f / ls;
  #pragma unroll
  for (int j = 0; j < 4; ++j) {
    short4v vv;
    vv[0] = f2bs(o2[j][0]*inv); vv[1] = f2bs(o2[j][1]*inv);
    vv[2] = f2bs(o2[j][2]*inv); vv[3] = f2bs(o2[j][3]*inv);
    *(short4v*)(attnb + (size_t)qrow*2048 + h*64 + (j>>1)*32 + (kb<<1) + ((j&1)<<2)) = vv;
  }
}

extern "C" void kernel_launch(void* const* d_in, const int* in_sizes, int n_in,
                              void* d_out, int out_size, void* d_ws, size_t ws_size,
                              hipStream_t stream) {
  const float* x    = (const float*)d_in[0];
  const float* cosb = (const float*)d_in[2];
  const float* sinb = (const float*)d_in[3];
  const float* Wq   = (const float*)d_in[4];
  const float* Wk   = (const float*)d_in[5];
  const float* Wv   = (const float*)d_in[6];
  const float* Wo   = (const float*)d_in[7];
  const float* qg   = (const float*)d_in[8];
  const float* kg   = (const float*)d_in[9];
  float* out = (float*)d_out;

  char* ws = (char*)d_ws;
  bf16*  xb    = (bf16*)(ws);                    // 8 MB  K-perm (live thru QKV GEMM)
  bf16*  WqT   = (bf16*)(ws + 8388608);          // 8 MB  K-perm
  bf16*  WkT   = (bf16*)(ws + 16777216);         // 2 MB  K-perm
  bf16*  WvT   = (bf16*)(ws + 18874368);         // 2 MB  K-perm (contiguous N=3072 B-panel)
  bf16*  WoT   = (bf16*)(ws + 20971520);         // 8 MB  K-perm (live until out-proj)
  bf16*  Qb    = (bf16*)(ws + 29360128);         // 8 MB  [32][2048][64] d-perm, x SCALE2
  bf16*  Kb    = (bf16*)(ws + 37748736);         // 2 MB  [8][2048][64] d-perm
  bf16*  Vt    = (bf16*)(ws + 41943040);         // 2 MB  [8][64][2048] kv-perm cols (direct)
  bf16*  attnb = (bf16*)(ws);                    // 8 MB  K-perm (overlays dead xb)

  k_prep<<<6656, 256, 0, stream>>>(x, Wq, Wk, Wv, Wo, xb, WqT, WkT, WvT, WoT);
  k_gemm_qkv<<<dim3(24, 16), 256, 0, stream>>>(xb, WqT, cosb, sinb, qg, kg, Qb, Kb, Vt, 2048);
  k_attn<<<512, 512, 0, stream>>>(Qb, Kb, Vt, attnb);
  k_gemm_out<<<dim3(16, 16), 256, 0, stream>>>(attnb, WoT, out, 2048, 2048, 2048, 2048);
}

// Round 16
// 164.016 us; speedup vs baseline: 1.0876x; 1.0876x over previous
//
#include <hip/hip_runtime.h>
#include <hip/hip_bf16.h>
#include <stdint.h>

typedef __hip_bfloat16 bf16;
typedef __attribute__((ext_vector_type(4))) short short4v;
typedef __attribute__((ext_vector_type(8))) short short8v;
typedef __attribute__((ext_vector_type(4))) float f32x4;

#define MFMA16(a,b,c) __builtin_amdgcn_mfma_f32_16x16x32_bf16(a,b,c,0,0,0)
#define SCALE2 0.18033688011f   /* (1/sqrt(64)) * log2(e) — folded into Qb */

__device__ __forceinline__ void gload16(const void* g, void* l) {
  __builtin_amdgcn_global_load_lds((const __attribute__((address_space(1))) unsigned int*)g,
                                   (__attribute__((address_space(3))) unsigned int*)l, 16, 0, 0);
}

__device__ __forceinline__ short f2bs(float f) {
  return __builtin_bit_cast(short, __float2bfloat16(f));
}

__device__ __forceinline__ float max3f(float a, float b, float c) {
  return fmaxf(fmaxf(a, b), c);      // clang fuses to v_max3_f32 (T17)
}

// K-dim permutation within each 32-group: lane-group g's MFMA fragment
// {4g..4g+3, 16+4g..16+4g+3} becomes 8 CONTIGUOUS elements at 8g..8g+7.
// p(k) = ((k&15)>>2)*8 + ((k>>4)&1)*4 + (k&3)
// Applied to GEMM K-dims (xb/W*/attnb), attn d-dim (Qb/Kb), attn kv-dim (Vt cols).

// ---------------- merged prelude: cvt_x (permuted) + 4 transpose_cvt (permuted) ----------------
__global__ __launch_bounds__(256) void k_prep(const float* __restrict__ x,
    const float* __restrict__ Wq, const float* __restrict__ Wk,
    const float* __restrict__ Wv, const float* __restrict__ Wo,
    bf16* __restrict__ xb, bf16* __restrict__ WqT, bf16* __restrict__ WkT,
    bf16* __restrict__ WvT, bf16* __restrict__ WoT) {
  __shared__ float ts[64][65];
  const int bid = blockIdx.x;
  const int t = threadIdx.x;
  if (bid < 4096) {
    int f = (bid*256 + t)*4;
    int row = f >> 11, c = f & 2047;
    float4 v = *(const float4*)(x + (size_t)row*2048 + c);
    int pc = (c & ~31) | (((c & 15) >> 2) << 3) | (((c >> 4) & 1) << 2);
    short4v o;
    o[0] = f2bs(v.x); o[1] = f2bs(v.y); o[2] = f2bs(v.z); o[3] = f2bs(v.w);
    *(short4v*)(xb + (size_t)row*2048 + pc) = o;
    return;
  }
  int tb = bid - 4096;
  const float* W; bf16* Wt; int K, N, bx, by;
  if (tb < 1024)      { W = Wq; Wt = WqT; K = 2048; N = 2048; bx = tb & 31;         by = tb >> 5; }
  else if (tb < 1280) { W = Wk; Wt = WkT; K = 2048; N = 512;  bx = (tb-1024) & 7;   by = (tb-1024) >> 3; }
  else if (tb < 1536) { W = Wv; Wt = WvT; K = 2048; N = 512;  bx = (tb-1280) & 7;   by = (tb-1280) >> 3; }
  else                { W = Wo; Wt = WoT; K = 2048; N = 2048; bx = (tb-1536) & 31;  by = (tb-1536) >> 5; }
  const int k0 = by*64, n0 = bx*64;
  #pragma unroll
  for (int ii = 0; ii < 16; ++ii) {
    int idx = ii*256 + t; int r = idx>>6, c = idx&63;
    ts[r][c] = W[(size_t)(k0+r)*N + n0 + c];
  }
  __syncthreads();
  #pragma unroll
  for (int ii = 0; ii < 16; ++ii) {
    int idx = ii*256 + t; int r = idx>>6, c = idx&63;   // r: n-row, c: k-col (logical)
    int pc = (c & 32) | (((c & 15) >> 2) << 3) | (((c >> 4) & 1) << 2) | (c & 3);
    Wt[(size_t)(n0+r)*K + k0 + pc] = __float2bfloat16(ts[c][r]);
  }
}

// ---------------- QKV GEMM, FUSED RMSNorm+RoPE epilogue, b128 frags ----------------
// Q-heads additionally scaled by SCALE2. Q/K outputs written with d-PERMUTED
// columns (so attn's QK^T fragments are contiguous b128).
__global__ __launch_bounds__(256) void k_gemm_qkv(const bf16* __restrict__ A, const bf16* __restrict__ Bt,
                                                  const float* __restrict__ cosb, const float* __restrict__ sinb,
                                                  const float* __restrict__ qg, const float* __restrict__ kg,
                                                  bf16* __restrict__ Qb, bf16* __restrict__ Kb,
                                                  bf16* __restrict__ Vb, int K) {
  __shared__ bf16 Asm[3][128*32];
  __shared__ bf16 Bsm[3][128*32];
  const int t = threadIdx.x;
  const int lane = t & 63, w = t >> 6;
  const int wr = w >> 1, wc = w & 1;
  const int m0 = blockIdx.y*128, n0 = blockIdx.x*128;
  const int l15 = lane & 15;
  const int g16 = (lane >> 4) << 4;

  f32x4 acc[4][4];
  #pragma unroll
  for (int i = 0; i < 4; ++i)
    #pragma unroll
    for (int j = 0; j < 4; ++j) acc[i][j] = 0.f;

  const char* Ab = (const char*)A;
  const char* Bb = (const char*)Bt;
  const int off  = t*16;
  const int srow = off >> 6;
  const int scolb = (((off >> 4) & 3) ^ ((srow >> 1) & 3)) << 4;

  const size_t arow0 = (size_t)(m0+srow)*K, arow1 = (size_t)(m0+srow+64)*K;
  const size_t brow0 = (size_t)(n0+srow)*K, brow1 = (size_t)(n0+srow+64)*K;

#define STAGE(buf, kk)  do {                                          \
    gload16(Ab + (arow0 + (kk))*2 + scolb, (char*)Asm[buf] + off);    \
    gload16(Ab + (arow1 + (kk))*2 + scolb, (char*)Asm[buf] + off + 4096); \
    gload16(Bb + (brow0 + (kk))*2 + scolb, (char*)Bsm[buf] + off);    \
    gload16(Bb + (brow1 + (kk))*2 + scolb, (char*)Bsm[buf] + off + 4096); \
  } while (0)

  const int nsteps = K >> 5;
  STAGE(0, 0);
  STAGE(1, 32);

  for (int it = 0; it < nsteps; ++it) {
    const int kf = (it + 2) << 5;
    if (kf < K) {
      STAGE((it + 2) % 3, kf);
      asm volatile("s_waitcnt vmcnt(8)" ::: "memory");
    } else if (it + 1 < nsteps) {
      asm volatile("s_waitcnt vmcnt(4)" ::: "memory");
    } else {
      asm volatile("s_waitcnt vmcnt(0)" ::: "memory");
    }
    __builtin_amdgcn_s_barrier();
    __builtin_amdgcn_sched_barrier(0);

    const char* Ac = (const char*)Asm[it % 3];
    const char* Bc = (const char*)Bsm[it % 3];
    short8v a[4], b[4];
    #pragma unroll
    for (int i = 0; i < 4; ++i) {
      const int arow = wr*64 + i*16 + l15;
      a[i] = *(const short8v*)(Ac + arow*64 + (g16 ^ (((arow >> 1) & 3) << 4)));
      const int brow = wc*64 + i*16 + l15;
      b[i] = *(const short8v*)(Bc + brow*64 + (g16 ^ (((brow >> 1) & 3) << 4)));
    }
    #pragma unroll
    for (int i = 0; i < 4; ++i)
      #pragma unroll
      for (int j = 0; j < 4; ++j)
        acc[i][j] = MFMA16(a[i], b[j], acc[i][j]);
    __builtin_amdgcn_sched_barrier(0);
    __builtin_amdgcn_s_barrier();
  }
#undef STAGE

  // ---- fused epilogue: rmsnorm + rope (Q/K, d-PERMUTED store) or plain cvt (V, logical) ----
  const int hh = (n0 + wc*64) >> 6;            // head id 0..47 (wave-uniform)
  float gam[4];
  if (hh < 40) {
    const float* gp = (hh < 32) ? qg : kg;
    #pragma unroll
    for (int j = 0; j < 4; ++j) gam[j] = gp[j*16 + l15];
    if (hh < 32) {
      #pragma unroll
      for (int j = 0; j < 4; ++j) gam[j] *= SCALE2;   // fold softmax scale into Q
    }
  }
  const int pbase = ((l15 >> 2) << 3) + (l15 & 3);   // d-perm base for this lane
  #pragma unroll
  for (int i = 0; i < 4; ++i) {
    #pragma unroll
    for (int rr = 0; rr < 4; ++rr) {
      const int row = m0 + wr*64 + i*16 + ((lane>>4)<<2) + rr;   // absolute s
      float v0 = acc[i][0][rr], v1 = acc[i][1][rr], v2 = acc[i][2][rr], v3 = acc[i][3][rr];
      if (hh < 40) {
        float ss = v0*v0 + v1*v1 + v2*v2 + v3*v3;
        ss += __shfl_xor(ss, 1); ss += __shfl_xor(ss, 2);
        ss += __shfl_xor(ss, 4); ss += __shfl_xor(ss, 8);
        const float rms = rsqrtf(ss*(1.0f/64.0f) + 1e-6f);
        const float t0 = v0*rms*gam[0], t1 = v1*rms*gam[1];
        const float t2 = v2*rms*gam[2], t3 = v3*rms*gam[3];
        const float* cr = cosb + (size_t)row*64;
        const float* sr = sinb + (size_t)row*64;
        const float o0 = t0*cr[l15]      - t2*sr[l15];
        const float o1 = t1*cr[16+l15]   - t3*sr[16+l15];
        const float o2 = t2*cr[32+l15]   + t0*sr[32+l15];
        const float o3 = t3*cr[48+l15]   + t1*sr[48+l15];
        bf16* dst = (hh < 32) ? (Qb + ((size_t)hh*2048 + row)*64)
                              : (Kb + ((size_t)(hh-32)*2048 + row)*64);
        // d-permuted positions: j -> (j>>1)*32 + pbase + (j&1)*4
        dst[pbase]          = __float2bfloat16(o0);
        dst[pbase + 4]      = __float2bfloat16(o1);
        dst[32 + pbase]     = __float2bfloat16(o2);
        dst[32 + pbase + 4] = __float2bfloat16(o3);
      } else {
        bf16* dst = Vb + ((size_t)(hh-40)*2048 + row)*64;
        dst[l15]      = __float2bfloat16(v0);
        dst[16 + l15] = __float2bfloat16(v1);
        dst[32 + l15] = __float2bfloat16(v2);
        dst[48 + l15] = __float2bfloat16(v3);
      }
    }
  }
}

// ---------------- out-proj GEMM: direct f32 store, b128 frags, depth-2 prefetch ----------------
__global__ __launch_bounds__(256) void k_gemm_out(const bf16* __restrict__ A, const bf16* __restrict__ Bt,
                                                  float* __restrict__ C, int M, int N, int K, int ldc) {
  __shared__ bf16 Asm[3][128*32];
  __shared__ bf16 Bsm[3][128*32];
  const int t = threadIdx.x;
  const int lane = t & 63, w = t >> 6;
  const int wr = w >> 1, wc = w & 1;
  const int m0 = blockIdx.y*128, n0 = blockIdx.x*128;
  const int l15 = lane & 15;
  const int g16 = (lane >> 4) << 4;

  f32x4 acc[4][4];
  #pragma unroll
  for (int i = 0; i < 4; ++i)
    #pragma unroll
    for (int j = 0; j < 4; ++j) acc[i][j] = 0.f;

  const char* Ab = (const char*)A;
  const char* Bb = (const char*)Bt;
  const int off  = t*16;
  const int srow = off >> 6;
  const int scolb = (((off >> 4) & 3) ^ ((srow >> 1) & 3)) << 4;

  const size_t arow0 = (size_t)(m0+srow)*K, arow1 = (size_t)(m0+srow+64)*K;
  const size_t brow0 = (size_t)(n0+srow)*K, brow1 = (size_t)(n0+srow+64)*K;

#define STAGE(buf, kk)  do {                                          \
    gload16(Ab + (arow0 + (kk))*2 + scolb, (char*)Asm[buf] + off);    \
    gload16(Ab + (arow1 + (kk))*2 + scolb, (char*)Asm[buf] + off + 4096); \
    gload16(Bb + (brow0 + (kk))*2 + scolb, (char*)Bsm[buf] + off);    \
    gload16(Bb + (brow1 + (kk))*2 + scolb, (char*)Bsm[buf] + off + 4096); \
  } while (0)

  const int nsteps = K >> 5;
  STAGE(0, 0);
  STAGE(1, 32);

  for (int it = 0; it < nsteps; ++it) {
    if (it + 2 < nsteps) {
      STAGE((it + 2) % 3, (it + 2) << 5);
      asm volatile("s_waitcnt vmcnt(8)" ::: "memory");
    } else if (it + 1 < nsteps) {
      asm volatile("s_waitcnt vmcnt(4)" ::: "memory");
    } else {
      asm volatile("s_waitcnt vmcnt(0)" ::: "memory");
    }
    __builtin_amdgcn_s_barrier();
    __builtin_amdgcn_sched_barrier(0);

    const char* Ac = (const char*)Asm[it % 3];
    const char* Bc = (const char*)Bsm[it % 3];
    short8v a[4], b[4];
    #pragma unroll
    for (int i = 0; i < 4; ++i) {
      const int arow = wr*64 + i*16 + l15;
      a[i] = *(const short8v*)(Ac + arow*64 + (g16 ^ (((arow >> 1) & 3) << 4)));
      const int brow = wc*64 + i*16 + l15;
      b[i] = *(const short8v*)(Bc + brow*64 + (g16 ^ (((brow >> 1) & 3) << 4)));
    }
    #pragma unroll
    for (int i = 0; i < 4; ++i)
      #pragma unroll
      for (int j = 0; j < 4; ++j)
        acc[i][j] = MFMA16(a[i], b[j], acc[i][j]);
    __builtin_amdgcn_sched_barrier(0);
    __builtin_amdgcn_s_barrier();
  }
#undef STAGE

  #pragma unroll
  for (int i = 0; i < 4; ++i) {
    int row0 = m0 + wr*64 + i*16 + ((lane>>4)<<2);
    #pragma unroll
    for (int j = 0; j < 4; ++j) {
      int col = n0 + wc*64 + j*16 + l15;
      #pragma unroll
      for (int r = 0; r < 4; ++r)
        C[(size_t)(row0+r)*ldc + col] = acc[i][j][r];
    }
  }
}

// ---------------- V transpose: Vb [8][2048][64] -> Vt [8][64][2048], kv-PERMUTED cols ----------------
__global__ __launch_bounds__(256) void k_vtrans(const bf16* __restrict__ Vb, bf16* __restrict__ Vt) {
  __shared__ bf16 ts[64][72];
  const int kv = blockIdx.y;
  const int s0 = blockIdx.x*64;
  const int t  = threadIdx.x;
  const bf16* src = Vb + ((size_t)kv*2048 + s0)*64;
  #pragma unroll
  for (int ii = 0; ii < 2; ++ii) {
    int idx = ii*256 + t;
    int s = idx >> 3, d8 = (idx & 7)*8;
    *(int4*)&ts[s][d8] = *(const int4*)(src + s*64 + d8);
  }
  __syncthreads();
  #pragma unroll
  for (int ii = 0; ii < 2; ++ii) {
    int idx = ii*256 + t;
    int d = idx >> 3, sB = (idx & 7)*8;      // storage-contiguous 8 cols at sB
    // storage sB+e <- logical (sB&32) + 4*((sB>>3)&3) + (e&3) + 16*(e>>2)
    const int w32 = sB & 32, lb = ((sB >> 3) & 3) << 2;
    short8v v;
    #pragma unroll
    for (int e = 0; e < 8; ++e)
      v[e] = __builtin_bit_cast(short, ts[w32 + lb + (e & 3) + ((e >> 2) << 4)][d]);
    *(short8v*)(Vt + (size_t)kv*64*2048 + (size_t)d*2048 + s0 + sB) = v;
  }
}

// ---------------- causal flash attention v6: b128 fragments everywhere ----------------
// Q/K d-permuted, Vt kv-permuted -> every MFMA operand is ONE aligned b128 read,
// zero CAT8/repack. pb packing already matches the permuted element order.
__global__ __launch_bounds__(512) void k_attn(const bf16* __restrict__ Qb, const bf16* __restrict__ Kb,
                                              const bf16* __restrict__ Vt, bf16* __restrict__ attnb) {
  __shared__ bf16 Ksm[128][72];   // stride 144 B: 16-aligned, 2-way banks (free)
  __shared__ bf16 Vsm[64][136];   // stride 272 B: 16-aligned, 2-way banks (free)
  const int t = threadIdx.x, lane = t & 63, w = t >> 6;
  const int bid = blockIdx.x;
  const int h = bid & 31;
  const int qi = 15 - (bid >> 5);          // heavy blocks first
  const int qb0 = qi * 128;
  const int kvh = h >> 2;
  const int kb = (lane>>4)*4;
  const int kb2 = kb << 1;                 // permuted-contiguous frag base (8g)
  const int l15 = lane & 15;

  const bf16* Qh = Qb + (size_t)h*2048*64;
  const bf16* Kh = Kb + (size_t)kvh*2048*64;
  const bf16* Vh = Vt + (size_t)kvh*64*2048;

  const int qrow = qb0 + w*16 + l15;       // this lane's q-row (replicated x4 groups)
  short8v qf[2];
  #pragma unroll
  for (int kk = 0; kk < 2; ++kk)
    qf[kk] = *(const short8v*)(Qh + (size_t)qrow*64 + kk*32 + kb2);

  float m_ = -3e38f, ls = 0.f;
  f32x4 o2[4];
  #pragma unroll
  for (int j = 0; j < 4; ++j) o2[j] = 0.f;

  const int nt = qi + 1;
  for (int tt = 0; tt < nt; ++tt) {
    #pragma unroll
    for (int ii = 0; ii < 2; ++ii) {
      int idx = ii*512 + t;
      int kr = idx >> 3, kc = (idx & 7)*8;
      *(int4*)(&Ksm[kr][kc]) = *(const int4*)(Kh + ((size_t)(tt*128 + kr))*64 + kc);
      int vr = idx >> 4, vc = (idx & 15)*8;
      *(int4*)(&Vsm[vr][vc]) = *(const int4*)(Vh + (size_t)vr*2048 + tt*128 + vc);
    }
    __syncthreads();

    // S^T = K Q^T -> sAcc[j]: kv-block j (0..7), q = l15 (pre-scaled via Q)
    f32x4 sAcc[8];
    #pragma unroll
    for (int j = 0; j < 8; ++j) sAcc[j] = 0.f;
    __builtin_amdgcn_s_setprio(1);
    #pragma unroll
    for (int kk = 0; kk < 2; ++kk) {
      #pragma unroll
      for (int j = 0; j < 8; ++j) {
        short8v ak = *(const short8v*)(&Ksm[j*16 + l15][kk*32 + kb2]);
        sAcc[j] = MFMA16(ak, qf[kk], sAcc[j]);
      }
    }
    __builtin_amdgcn_s_setprio(0);

    float p[8][4];
    #pragma unroll
    for (int j = 0; j < 8; ++j)
      #pragma unroll
      for (int r = 0; r < 4; ++r) p[j][r] = sAcc[j][r];
    if (tt == nt - 1) {                      // diagonal tile: causal mask
      #pragma unroll
      for (int j = 0; j < 8; ++j) {
        #pragma unroll
        for (int r = 0; r < 4; ++r)
          if (tt*128 + j*16 + kb + r > qrow) p[j][r] = -3e38f;
      }
    }

    // row max: max3 tree + cross-group combine
    float mj[8];
    #pragma unroll
    for (int j = 0; j < 8; ++j)
      mj[j] = fmaxf(max3f(p[j][0], p[j][1], p[j][2]), p[j][3]);
    float mx = fmaxf(max3f(mj[0], mj[1], mj[2]), max3f(mj[3], mj[4], mj[5]));
    mx = max3f(mx, mj[6], mj[7]);
    mx = fmaxf(mx, __shfl_xor(mx, 16));
    mx = fmaxf(mx, __shfl_xor(mx, 32));

    // defer-max (T13): skip rescale when tile max within 8 of running max
    float mn = m_;
    if (!__all(mx <= m_ + 8.f)) {
      mn = fmaxf(m_, mx);
      float alpha = exp2f(m_ - mn);
      m_ = mn;
      ls *= alpha;
      #pragma unroll
      for (int j = 0; j < 4; ++j) o2[j] *= alpha;
    }

    float rs = 0.f;
    #pragma unroll
    for (int j = 0; j < 8; ++j)
      #pragma unroll
      for (int r = 0; r < 4; ++r) {
        float e = exp2f(p[j][r] - mn);
        p[j][r] = e;
        rs += e;
      }
    rs += __shfl_xor(rs, 16);
    rs += __shfl_xor(rs, 32);
    ls += rs;

    short8v pb[4];
    #pragma unroll
    for (int kk = 0; kk < 4; ++kk) {
      short8v v;
      v[0] = f2bs(p[2*kk][0]);   v[1] = f2bs(p[2*kk][1]);
      v[2] = f2bs(p[2*kk][2]);   v[3] = f2bs(p[2*kk][3]);
      v[4] = f2bs(p[2*kk+1][0]); v[5] = f2bs(p[2*kk+1][1]);
      v[6] = f2bs(p[2*kk+1][2]); v[7] = f2bs(p[2*kk+1][3]);
      pb[kk] = v;
    }

    // O^T += V^T P -> o2[j]: d-block j, q = l15 (V kv-permuted -> b128 frags)
    __builtin_amdgcn_s_setprio(1);
    #pragma unroll
    for (int kk = 0; kk < 4; ++kk) {
      #pragma unroll
      for (int j = 0; j < 4; ++j) {
        short8v av = *(const short8v*)(&Vsm[j*16 + l15][kk*32 + kb2]);
        o2[j] = MFMA16(av, pb[kk], o2[j]);
      }
    }
    __builtin_amdgcn_s_setprio(0);
    __syncthreads();
  }

  // write attnb in K-PERMUTED layout (out-proj A-operand)
  float inv = 1.0f / ls;
  #pragma unroll
  for (int j = 0; j < 4; ++j) {
    short4v vv;
    vv[0] = f2bs(o2[j][0]*inv); vv[1] = f2bs(o2[j][1]*inv);
    vv[2] = f2bs(o2[j][2]*inv); vv[3] = f2bs(o2[j][3]*inv);
    *(short4v*)(attnb + (size_t)qrow*2048 + h*64 + (j>>1)*32 + (kb<<1) + ((j&1)<<2)) = vv;
  }
}

extern "C" void kernel_launch(void* const* d_in, const int* in_sizes, int n_in,
                              void* d_out, int out_size, void* d_ws, size_t ws_size,
                              hipStream_t stream) {
  const float* x    = (const float*)d_in[0];
  const float* cosb = (const float*)d_in[2];
  const float* sinb = (const float*)d_in[3];
  const float* Wq   = (const float*)d_in[4];
  const float* Wk   = (const float*)d_in[5];
  const float* Wv   = (const float*)d_in[6];
  const float* Wo   = (const float*)d_in[7];
  const float* qg   = (const float*)d_in[8];
  const float* kg   = (const float*)d_in[9];
  float* out = (float*)d_out;

  char* ws = (char*)d_ws;
  bf16*  xb    = (bf16*)(ws);                    // 8 MB  K-perm (live thru QKV GEMM)
  bf16*  WqT   = (bf16*)(ws + 8388608);          // 8 MB  K-perm
  bf16*  WkT   = (bf16*)(ws + 16777216);         // 2 MB  K-perm
  bf16*  WvT   = (bf16*)(ws + 18874368);         // 2 MB  K-perm (contiguous N=3072 B-panel)
  bf16*  WoT   = (bf16*)(ws + 20971520);         // 8 MB  K-perm (live until out-proj)
  bf16*  Qb    = (bf16*)(ws + 29360128);         // 8 MB  [32][2048][64] d-perm, x SCALE2
  bf16*  Kb    = (bf16*)(ws + 37748736);         // 2 MB  [8][2048][64] d-perm
  bf16*  Vb    = (bf16*)(ws + 39845888);         // 2 MB  [8][2048][64] logical
  bf16*  Vt    = (bf16*)(ws + 41943040);         // 2 MB  [8][64][2048] kv-perm cols
  bf16*  attnb = (bf16*)(ws);                    // 8 MB  K-perm (overlays dead xb)

  k_prep<<<6656, 256, 0, stream>>>(x, Wq, Wk, Wv, Wo, xb, WqT, WkT, WvT, WoT);
  k_gemm_qkv<<<dim3(24, 16), 256, 0, stream>>>(xb, WqT, cosb, sinb, qg, kg, Qb, Kb, Vb, 2048);
  k_vtrans<<<dim3(32, 8), 256, 0, stream>>>(Vb, Vt);
  k_attn<<<512, 512, 0, stream>>>(Qb, Kb, Vt, attnb);
  k_gemm_out<<<dim3(16, 16), 256, 0, stream>>>(attnb, WoT, out, 2048, 2048, 2048, 2048);
}

// Round 17
// 158.938 us; speedup vs baseline: 1.1223x; 1.0319x over previous
//
#include <hip/hip_runtime.h>
#include <hip/hip_bf16.h>
#include <stdint.h>

typedef __hip_bfloat16 bf16;
typedef __attribute__((ext_vector_type(4))) short short4v;
typedef __attribute__((ext_vector_type(8))) short short8v;
typedef __attribute__((ext_vector_type(4))) float f32x4;

#define MFMA16(a,b,c) __builtin_amdgcn_mfma_f32_16x16x32_bf16(a,b,c,0,0,0)
#define SCALE2 0.18033688011f   /* (1/sqrt(64)) * log2(e) — folded into Qb */

__device__ __forceinline__ void gload16(const void* g, void* l) {
  __builtin_amdgcn_global_load_lds((const __attribute__((address_space(1))) unsigned int*)g,
                                   (__attribute__((address_space(3))) unsigned int*)l, 16, 0, 0);
}

__device__ __forceinline__ short f2bs(float f) {
  return __builtin_bit_cast(short, __float2bfloat16(f));
}

__device__ __forceinline__ float max3f(float a, float b, float c) {
  return fmaxf(fmaxf(a, b), c);      // clang fuses to v_max3_f32 (T17)
}

// K-dim permutation within each 32-group: lane-group g's MFMA fragment
// {4g..4g+3, 16+4g..16+4g+3} becomes 8 CONTIGUOUS elements at 8g..8g+7.
// p(k) = ((k&15)>>2)*8 + ((k>>4)&1)*4 + (k&3)
// Applied to GEMM K-dims (xb/W*/attnb), attn d-dim (Qb/Kb), attn kv-dim (Vt cols).

// ---------------- merged prelude: cvt_x (permuted) + 4 transpose_cvt (permuted, b64 stores) ----------------
__global__ __launch_bounds__(256) void k_prep(const float* __restrict__ x,
    const float* __restrict__ Wq, const float* __restrict__ Wk,
    const float* __restrict__ Wv, const float* __restrict__ Wo,
    bf16* __restrict__ xb, bf16* __restrict__ WqT, bf16* __restrict__ WkT,
    bf16* __restrict__ WvT, bf16* __restrict__ WoT) {
  __shared__ float ts[64][65];
  const int bid = blockIdx.x;
  const int t = threadIdx.x;
  if (bid < 4096) {
    int f = (bid*256 + t)*4;
    int row = f >> 11, c = f & 2047;
    float4 v = *(const float4*)(x + (size_t)row*2048 + c);
    int pc = (c & ~31) | (((c & 15) >> 2) << 3) | (((c >> 4) & 1) << 2);
    short4v o;
    o[0] = f2bs(v.x); o[1] = f2bs(v.y); o[2] = f2bs(v.z); o[3] = f2bs(v.w);
    *(short4v*)(xb + (size_t)row*2048 + pc) = o;
    return;
  }
  int tb = bid - 4096;
  const float* W; bf16* Wt; int K, N, bx, by;
  if (tb < 1024)      { W = Wq; Wt = WqT; K = 2048; N = 2048; bx = tb & 31;         by = tb >> 5; }
  else if (tb < 1280) { W = Wk; Wt = WkT; K = 2048; N = 512;  bx = (tb-1024) & 7;   by = (tb-1024) >> 3; }
  else if (tb < 1536) { W = Wv; Wt = WvT; K = 2048; N = 512;  bx = (tb-1280) & 7;   by = (tb-1280) >> 3; }
  else                { W = Wo; Wt = WoT; K = 2048; N = 2048; bx = (tb-1536) & 31;  by = (tb-1536) >> 5; }
  const int k0 = by*64, n0 = bx*64;
  #pragma unroll
  for (int ii = 0; ii < 16; ++ii) {
    int idx = ii*256 + t; int r = idx>>6, c = idx&63;
    ts[r][c] = W[(size_t)(k0+r)*N + n0 + c];
  }
  __syncthreads();
  // vectorized permuted store: 4 logical k-cols (one quad) -> contiguous short4v
  #pragma unroll
  for (int ii = 0; ii < 4; ++ii) {
    int idx = ii*256 + t;
    int r = idx >> 4;                 // n-row 0..63
    int q = idx & 15;                 // k-quad 0..15
    int c = q << 2;                   // logical k base
    int pcb = ((q & 8) << 2) | ((q & 3) << 3) | (q & 4);   // permuted quad base
    short4v o;
    o[0] = f2bs(ts[c][r]);   o[1] = f2bs(ts[c+1][r]);
    o[2] = f2bs(ts[c+2][r]); o[3] = f2bs(ts[c+3][r]);
    *(short4v*)(Wt + (size_t)(n0+r)*K + k0 + pcb) = o;
  }
}

// ---------------- QKV GEMM, FUSED RMSNorm+RoPE epilogue, b128 frags ----------------
// Q-heads additionally scaled by SCALE2. Q/K written d-PERMUTED; V written
// DIRECTLY TRANSPOSED into Vt [kv][64 d][2048 s-perm] (vtrans kernel eliminated).
__global__ __launch_bounds__(256) void k_gemm_qkv(const bf16* __restrict__ A, const bf16* __restrict__ Bt,
                                                  const float* __restrict__ cosb, const float* __restrict__ sinb,
                                                  const float* __restrict__ qg, const float* __restrict__ kg,
                                                  bf16* __restrict__ Qb, bf16* __restrict__ Kb,
                                                  bf16* __restrict__ Vt, int K) {
  __shared__ bf16 Asm[3][128*32];
  __shared__ bf16 Bsm[3][128*32];
  const int t = threadIdx.x;
  const int lane = t & 63, w = t >> 6;
  const int wr = w >> 1, wc = w & 1;
  const int m0 = blockIdx.y*128, n0 = blockIdx.x*128;
  const int l15 = lane & 15;
  const int g16 = (lane >> 4) << 4;

  f32x4 acc[4][4];
  #pragma unroll
  for (int i = 0; i < 4; ++i)
    #pragma unroll
    for (int j = 0; j < 4; ++j) acc[i][j] = 0.f;

  const char* Ab = (const char*)A;
  const char* Bb = (const char*)Bt;
  const int off  = t*16;
  const int srow = off >> 6;
  const int scolb = (((off >> 4) & 3) ^ ((srow >> 1) & 3)) << 4;

  const size_t arow0 = (size_t)(m0+srow)*K, arow1 = (size_t)(m0+srow+64)*K;
  const size_t brow0 = (size_t)(n0+srow)*K, brow1 = (size_t)(n0+srow+64)*K;

#define STAGE(buf, kk)  do {                                          \
    gload16(Ab + (arow0 + (kk))*2 + scolb, (char*)Asm[buf] + off);    \
    gload16(Ab + (arow1 + (kk))*2 + scolb, (char*)Asm[buf] + off + 4096); \
    gload16(Bb + (brow0 + (kk))*2 + scolb, (char*)Bsm[buf] + off);    \
    gload16(Bb + (brow1 + (kk))*2 + scolb, (char*)Bsm[buf] + off + 4096); \
  } while (0)

  const int nsteps = K >> 5;
  STAGE(0, 0);
  STAGE(1, 32);

  for (int it = 0; it < nsteps; ++it) {
    const int kf = (it + 2) << 5;
    if (kf < K) {
      STAGE((it + 2) % 3, kf);
      asm volatile("s_waitcnt vmcnt(8)" ::: "memory");
    } else if (it + 1 < nsteps) {
      asm volatile("s_waitcnt vmcnt(4)" ::: "memory");
    } else {
      asm volatile("s_waitcnt vmcnt(0)" ::: "memory");
    }
    __builtin_amdgcn_s_barrier();
    __builtin_amdgcn_sched_barrier(0);

    const char* Ac = (const char*)Asm[it % 3];
    const char* Bc = (const char*)Bsm[it % 3];
    short8v a[4], b[4];
    #pragma unroll
    for (int i = 0; i < 4; ++i) {
      const int arow = wr*64 + i*16 + l15;
      a[i] = *(const short8v*)(Ac + arow*64 + (g16 ^ (((arow >> 1) & 3) << 4)));
      const int brow = wc*64 + i*16 + l15;
      b[i] = *(const short8v*)(Bc + brow*64 + (g16 ^ (((brow >> 1) & 3) << 4)));
    }
    #pragma unroll
    for (int i = 0; i < 4; ++i)
      #pragma unroll
      for (int j = 0; j < 4; ++j)
        acc[i][j] = MFMA16(a[i], b[j], acc[i][j]);
    __builtin_amdgcn_sched_barrier(0);
    __builtin_amdgcn_s_barrier();
  }
#undef STAGE

  // ---- fused epilogue ----
  const int hh = (n0 + wc*64) >> 6;            // head id 0..47 (wave-uniform)
  if (hh < 40) {
    // rmsnorm + rope, d-PERMUTED store
    float gam[4];
    const float* gp = (hh < 32) ? qg : kg;
    #pragma unroll
    for (int j = 0; j < 4; ++j) gam[j] = gp[j*16 + l15];
    if (hh < 32) {
      #pragma unroll
      for (int j = 0; j < 4; ++j) gam[j] *= SCALE2;   // fold softmax scale into Q
    }
    const int pbase = ((l15 >> 2) << 3) + (l15 & 3);   // d-perm base for this lane
    #pragma unroll
    for (int i = 0; i < 4; ++i) {
      #pragma unroll
      for (int rr = 0; rr < 4; ++rr) {
        const int row = m0 + wr*64 + i*16 + ((lane>>4)<<2) + rr;   // absolute s
        float v0 = acc[i][0][rr], v1 = acc[i][1][rr], v2 = acc[i][2][rr], v3 = acc[i][3][rr];
        float ss = v0*v0 + v1*v1 + v2*v2 + v3*v3;
        ss += __shfl_xor(ss, 1); ss += __shfl_xor(ss, 2);
        ss += __shfl_xor(ss, 4); ss += __shfl_xor(ss, 8);
        const float rms = rsqrtf(ss*(1.0f/64.0f) + 1e-6f);
        const float t0 = v0*rms*gam[0], t1 = v1*rms*gam[1];
        const float t2 = v2*rms*gam[2], t3 = v3*rms*gam[3];
        const float* cr = cosb + (size_t)row*64;
        const float* sr = sinb + (size_t)row*64;
        const float o0 = t0*cr[l15]      - t2*sr[l15];
        const float o1 = t1*cr[16+l15]   - t3*sr[16+l15];
        const float o2 = t2*cr[32+l15]   + t0*sr[32+l15];
        const float o3 = t3*cr[48+l15]   + t1*sr[48+l15];
        bf16* dst = (hh < 32) ? (Qb + ((size_t)hh*2048 + row)*64)
                              : (Kb + ((size_t)(hh-32)*2048 + row)*64);
        dst[pbase]          = __float2bfloat16(o0);
        dst[pbase + 4]      = __float2bfloat16(o1);
        dst[32 + pbase]     = __float2bfloat16(o2);
        dst[32 + pbase + 4] = __float2bfloat16(o3);
      }
    }
  } else {
    // V: direct transposed store into Vt [kv][d][s-perm]; the 4 rr-values of
    // each (i,j) form one contiguous permuted quad -> short4v store.
    bf16* dstT = Vt + (size_t)(hh-40)*64*2048;
    #pragma unroll
    for (int i = 0; i < 4; ++i) {
      const int s_log = m0 + wr*64 + i*16 + ((lane>>4)<<2);   // 4-aligned quad base
      const int a_  = (s_log >> 2) & 7;                        // quad idx in 32-group
      const int ps  = (s_log & ~31) + ((a_ & 3) << 3) + ((a_ >> 2) << 2);
      #pragma unroll
      for (int j = 0; j < 4; ++j) {
        const int d = j*16 + l15;
        short4v vv;
        vv[0] = f2bs(acc[i][j][0]); vv[1] = f2bs(acc[i][j][1]);
        vv[2] = f2bs(acc[i][j][2]); vv[3] = f2bs(acc[i][j][3]);
        *(short4v*)(dstT + (size_t)d*2048 + ps) = vv;
      }
    }
  }
}

// ---------------- out-proj GEMM: direct f32 store, b128 frags, depth-2 prefetch ----------------
__global__ __launch_bounds__(256) void k_gemm_out(const bf16* __restrict__ A, const bf16* __restrict__ Bt,
                                                  float* __restrict__ C, int M, int N, int K, int ldc) {
  __shared__ bf16 Asm[3][128*32];
  __shared__ bf16 Bsm[3][128*32];
  const int t = threadIdx.x;
  const int lane = t & 63, w = t >> 6;
  const int wr = w >> 1, wc = w & 1;
  const int m0 = blockIdx.y*128, n0 = blockIdx.x*128;
  const int l15 = lane & 15;
  const int g16 = (lane >> 4) << 4;

  f32x4 acc[4][4];
  #pragma unroll
  for (int i = 0; i < 4; ++i)
    #pragma unroll
    for (int j = 0; j < 4; ++j) acc[i][j] = 0.f;

  const char* Ab = (const char*)A;
  const char* Bb = (const char*)Bt;
  const int off  = t*16;
  const int srow = off >> 6;
  const int scolb = (((off >> 4) & 3) ^ ((srow >> 1) & 3)) << 4;

  const size_t arow0 = (size_t)(m0+srow)*K, arow1 = (size_t)(m0+srow+64)*K;
  const size_t brow0 = (size_t)(n0+srow)*K, brow1 = (size_t)(n0+srow+64)*K;

#define STAGE(buf, kk)  do {                                          \
    gload16(Ab + (arow0 + (kk))*2 + scolb, (char*)Asm[buf] + off);    \
    gload16(Ab + (arow1 + (kk))*2 + scolb, (char*)Asm[buf] + off + 4096); \
    gload16(Bb + (brow0 + (kk))*2 + scolb, (char*)Bsm[buf] + off);    \
    gload16(Bb + (brow1 + (kk))*2 + scolb, (char*)Bsm[buf] + off + 4096); \
  } while (0)

  const int nsteps = K >> 5;
  STAGE(0, 0);
  STAGE(1, 32);

  for (int it = 0; it < nsteps; ++it) {
    if (it + 2 < nsteps) {
      STAGE((it + 2) % 3, (it + 2) << 5);
      asm volatile("s_waitcnt vmcnt(8)" ::: "memory");
    } else if (it + 1 < nsteps) {
      asm volatile("s_waitcnt vmcnt(4)" ::: "memory");
    } else {
      asm volatile("s_waitcnt vmcnt(0)" ::: "memory");
    }
    __builtin_amdgcn_s_barrier();
    __builtin_amdgcn_sched_barrier(0);

    const char* Ac = (const char*)Asm[it % 3];
    const char* Bc = (const char*)Bsm[it % 3];
    short8v a[4], b[4];
    #pragma unroll
    for (int i = 0; i < 4; ++i) {
      const int arow = wr*64 + i*16 + l15;
      a[i] = *(const short8v*)(Ac + arow*64 + (g16 ^ (((arow >> 1) & 3) << 4)));
      const int brow = wc*64 + i*16 + l15;
      b[i] = *(const short8v*)(Bc + brow*64 + (g16 ^ (((brow >> 1) & 3) << 4)));
    }
    #pragma unroll
    for (int i = 0; i < 4; ++i)
      #pragma unroll
      for (int j = 0; j < 4; ++j)
        acc[i][j] = MFMA16(a[i], b[j], acc[i][j]);
    __builtin_amdgcn_sched_barrier(0);
    __builtin_amdgcn_s_barrier();
  }
#undef STAGE

  #pragma unroll
  for (int i = 0; i < 4; ++i) {
    int row0 = m0 + wr*64 + i*16 + ((lane>>4)<<2);
    #pragma unroll
    for (int j = 0; j < 4; ++j) {
      int col = n0 + wc*64 + j*16 + l15;
      #pragma unroll
      for (int r = 0; r < 4; ++r)
        C[(size_t)(row0+r)*ldc + col] = acc[i][j][r];
    }
  }
}

// ---------------- causal flash attention v6: b128 fragments everywhere ----------------
__global__ __launch_bounds__(512) void k_attn(const bf16* __restrict__ Qb, const bf16* __restrict__ Kb,
                                              const bf16* __restrict__ Vt, bf16* __restrict__ attnb) {
  __shared__ bf16 Ksm[128][72];   // stride 144 B: 16-aligned, 2-way banks (free)
  __shared__ bf16 Vsm[64][136];   // stride 272 B: 16-aligned, 2-way banks (free)
  const int t = threadIdx.x, lane = t & 63, w = t >> 6;
  const int bid = blockIdx.x;
  const int h = bid & 31;
  const int qi = 15 - (bid >> 5);          // heavy blocks first
  const int qb0 = qi * 128;
  const int kvh = h >> 2;
  const int kb = (lane>>4)*4;
  const int kb2 = kb << 1;                 // permuted-contiguous frag base (8g)
  const int l15 = lane & 15;

  const bf16* Qh = Qb + (size_t)h*2048*64;
  const bf16* Kh = Kb + (size_t)kvh*2048*64;
  const bf16* Vh = Vt + (size_t)kvh*64*2048;

  const int qrow = qb0 + w*16 + l15;       // this lane's q-row (replicated x4 groups)
  short8v qf[2];
  #pragma unroll
  for (int kk = 0; kk < 2; ++kk)
    qf[kk] = *(const short8v*)(Qh + (size_t)qrow*64 + kk*32 + kb2);

  float m_ = -3e38f, ls = 0.f;
  f32x4 o2[4];
  #pragma unroll
  for (int j = 0; j < 4; ++j) o2[j] = 0.f;

  const int nt = qi + 1;
  for (int tt = 0; tt < nt; ++tt) {
    #pragma unroll
    for (int ii = 0; ii < 2; ++ii) {
      int idx = ii*512 + t;
      int kr = idx >> 3, kc = (idx & 7)*8;
      *(int4*)(&Ksm[kr][kc]) = *(const int4*)(Kh + ((size_t)(tt*128 + kr))*64 + kc);
      int vr = idx >> 4, vc = (idx & 15)*8;
      *(int4*)(&Vsm[vr][vc]) = *(const int4*)(Vh + (size_t)vr*2048 + tt*128 + vc);
    }
    __syncthreads();

    // S^T = K Q^T -> sAcc[j]: kv-block j (0..7), q = l15 (pre-scaled via Q)
    f32x4 sAcc[8];
    #pragma unroll
    for (int j = 0; j < 8; ++j) sAcc[j] = 0.f;
    __builtin_amdgcn_s_setprio(1);
    #pragma unroll
    for (int kk = 0; kk < 2; ++kk) {
      #pragma unroll
      for (int j = 0; j < 8; ++j) {
        short8v ak = *(const short8v*)(&Ksm[j*16 + l15][kk*32 + kb2]);
        sAcc[j] = MFMA16(ak, qf[kk], sAcc[j]);
      }
    }
    __builtin_amdgcn_s_setprio(0);

    float p[8][4];
    #pragma unroll
    for (int j = 0; j < 8; ++j)
      #pragma unroll
      for (int r = 0; r < 4; ++r) p[j][r] = sAcc[j][r];
    if (tt == nt - 1) {                      // diagonal tile: causal mask
      #pragma unroll
      for (int j = 0; j < 8; ++j) {
        #pragma unroll
        for (int r = 0; r < 4; ++r)
          if (tt*128 + j*16 + kb + r > qrow) p[j][r] = -3e38f;
      }
    }

    // row max: max3 tree + cross-group combine
    float mj[8];
    #pragma unroll
    for (int j = 0; j < 8; ++j)
      mj[j] = fmaxf(max3f(p[j][0], p[j][1], p[j][2]), p[j][3]);
    float mx = fmaxf(max3f(mj[0], mj[1], mj[2]), max3f(mj[3], mj[4], mj[5]));
    mx = max3f(mx, mj[6], mj[7]);
    mx = fmaxf(mx, __shfl_xor(mx, 16));
    mx = fmaxf(mx, __shfl_xor(mx, 32));

    // defer-max (T13): skip rescale when tile max within 8 of running max
    float mn = m_;
    if (!__all(mx <= m_ + 8.f)) {
      mn = fmaxf(m_, mx);
      float alpha = exp2f(m_ - mn);
      m_ = mn;
      ls *= alpha;
      #pragma unroll
      for (int j = 0; j < 4; ++j) o2[j] *= alpha;
    }

    float rs = 0.f;
    #pragma unroll
    for (int j = 0; j < 8; ++j)
      #pragma unroll
      for (int r = 0; r < 4; ++r) {
        float e = exp2f(p[j][r] - mn);
        p[j][r] = e;
        rs += e;
      }
    rs += __shfl_xor(rs, 16);
    rs += __shfl_xor(rs, 32);
    ls += rs;

    short8v pb[4];
    #pragma unroll
    for (int kk = 0; kk < 4; ++kk) {
      short8v v;
      v[0] = f2bs(p[2*kk][0]);   v[1] = f2bs(p[2*kk][1]);
      v[2] = f2bs(p[2*kk][2]);   v[3] = f2bs(p[2*kk][3]);
      v[4] = f2bs(p[2*kk+1][0]); v[5] = f2bs(p[2*kk+1][1]);
      v[6] = f2bs(p[2*kk+1][2]); v[7] = f2bs(p[2*kk+1][3]);
      pb[kk] = v;
    }

    // O^T += V^T P -> o2[j]: d-block j, q = l15 (V kv-permuted -> b128 frags)
    __builtin_amdgcn_s_setprio(1);
    #pragma unroll
    for (int kk = 0; kk < 4; ++kk) {
      #pragma unroll
      for (int j = 0; j < 4; ++j) {
        short8v av = *(const short8v*)(&Vsm[j*16 + l15][kk*32 + kb2]);
        o2[j] = MFMA16(av, pb[kk], o2[j]);
      }
    }
    __builtin_amdgcn_s_setprio(0);
    __syncthreads();
  }

  // write attnb in K-PERMUTED layout (out-proj A-operand)
  float inv = 1.0f / ls;
  #pragma unroll
  for (int j = 0; j < 4; ++j) {
    short4v vv;
    vv[0] = f2bs(o2[j][0]*inv); vv[1] = f2bs(o2[j][1]*inv);
    vv[2] = f2bs(o2[j][2]*inv); vv[3] = f2bs(o2[j][3]*inv);
    *(short4v*)(attnb + (size_t)qrow*2048 + h*64 + (j>>1)*32 + (kb<<1) + ((j&1)<<2)) = vv;
  }
}

extern "C" void kernel_launch(void* const* d_in, const int* in_sizes, int n_in,
                              void* d_out, int out_size, void* d_ws, size_t ws_size,
                              hipStream_t stream) {
  const float* x    = (const float*)d_in[0];
  const float* cosb = (const float*)d_in[2];
  const float* sinb = (const float*)d_in[3];
  const float* Wq   = (const float*)d_in[4];
  const float* Wk   = (const float*)d_in[5];
  const float* Wv   = (const float*)d_in[6];
  const float* Wo   = (const float*)d_in[7];
  const float* qg   = (const float*)d_in[8];
  const float* kg   = (const float*)d_in[9];
  float* out = (float*)d_out;

  char* ws = (char*)d_ws;
  bf16*  xb    = (bf16*)(ws);                    // 8 MB  K-perm (live thru QKV GEMM)
  bf16*  WqT   = (bf16*)(ws + 8388608);          // 8 MB  K-perm
  bf16*  WkT   = (bf16*)(ws + 16777216);         // 2 MB  K-perm
  bf16*  WvT   = (bf16*)(ws + 18874368);         // 2 MB  K-perm (contiguous N=3072 B-panel)
  bf16*  WoT   = (bf16*)(ws + 20971520);         // 8 MB  K-perm (live until out-proj)
  bf16*  Qb    = (bf16*)(ws + 29360128);         // 8 MB  [32][2048][64] d-perm, x SCALE2
  bf16*  Kb    = (bf16*)(ws + 37748736);         // 2 MB  [8][2048][64] d-perm
  bf16*  Vt    = (bf16*)(ws + 41943040);         // 2 MB  [8][64][2048] kv-perm cols (direct)
  bf16*  attnb = (bf16*)(ws);                    // 8 MB  K-perm (overlays dead xb)

  k_prep<<<6656, 256, 0, stream>>>(x, Wq, Wk, Wv, Wo, xb, WqT, WkT, WvT, WoT);
  k_gemm_qkv<<<dim3(24, 16), 256, 0, stream>>>(xb, WqT, cosb, sinb, qg, kg, Qb, Kb, Vt, 2048);
  k_attn<<<512, 512, 0, stream>>>(Qb, Kb, Vt, attnb);
  k_gemm_out<<<dim3(16, 16), 256, 0, stream>>>(attnb, WoT, out, 2048, 2048, 2048, 2048);
}

// Round 18
// 158.024 us; speedup vs baseline: 1.1288x; 1.0058x over previous
//
#include <hip/hip_runtime.h>
#include <hip/hip_bf16.h>
#include <stdint.h>

typedef __hip_bfloat16 bf16;
typedef __attribute__((ext_vector_type(4))) short short4v;
typedef __attribute__((ext_vector_type(8))) short short8v;
typedef __attribute__((ext_vector_type(4))) float f32x4;

#define MFMA16(a,b,c) __builtin_amdgcn_mfma_f32_16x16x32_bf16(a,b,c,0,0,0)
#define SCALE2 0.18033688011f   /* (1/sqrt(64)) * log2(e) — folded into Qb */

__device__ __forceinline__ void gload16(const void* g, void* l) {
  __builtin_amdgcn_global_load_lds((const __attribute__((address_space(1))) unsigned int*)g,
                                   (__attribute__((address_space(3))) unsigned int*)l, 16, 0, 0);
}

__device__ __forceinline__ short f2bs(float f) {
  return __builtin_bit_cast(short, __float2bfloat16(f));
}

__device__ __forceinline__ float max3f(float a, float b, float c) {
  return fmaxf(fmaxf(a, b), c);      // clang fuses to v_max3_f32 (T17)
}

// K-dim permutation within each 32-group: lane-group g's MFMA fragment
// {4g..4g+3, 16+4g..16+4g+3} becomes 8 CONTIGUOUS elements at 8g..8g+7.
// p(k) = ((k&15)>>2)*8 + ((k>>4)&1)*4 + (k&3)
// Applied to GEMM K-dims (xb/W*/attnb), attn d-dim (Qb/Kb), attn kv-dim (Vt cols).

// ---------------- merged prelude: cvt_x (permuted) + 4 transpose_cvt (permuted, b64 stores) ----------------
__global__ __launch_bounds__(256) void k_prep(const float* __restrict__ x,
    const float* __restrict__ Wq, const float* __restrict__ Wk,
    const float* __restrict__ Wv, const float* __restrict__ Wo,
    bf16* __restrict__ xb, bf16* __restrict__ WqT, bf16* __restrict__ WkT,
    bf16* __restrict__ WvT, bf16* __restrict__ WoT) {
  __shared__ float ts[64][65];
  const int bid = blockIdx.x;
  const int t = threadIdx.x;
  if (bid < 4096) {
    int f = (bid*256 + t)*4;
    int row = f >> 11, c = f & 2047;
    float4 v = *(const float4*)(x + (size_t)row*2048 + c);
    int pc = (c & ~31) | (((c & 15) >> 2) << 3) | (((c >> 4) & 1) << 2);
    short4v o;
    o[0] = f2bs(v.x); o[1] = f2bs(v.y); o[2] = f2bs(v.z); o[3] = f2bs(v.w);
    *(short4v*)(xb + (size_t)row*2048 + pc) = o;
    return;
  }
  int tb = bid - 4096;
  const float* W; bf16* Wt; int K, N, bx, by;
  if (tb < 1024)      { W = Wq; Wt = WqT; K = 2048; N = 2048; bx = tb & 31;         by = tb >> 5; }
  else if (tb < 1280) { W = Wk; Wt = WkT; K = 2048; N = 512;  bx = (tb-1024) & 7;   by = (tb-1024) >> 3; }
  else if (tb < 1536) { W = Wv; Wt = WvT; K = 2048; N = 512;  bx = (tb-1280) & 7;   by = (tb-1280) >> 3; }
  else                { W = Wo; Wt = WoT; K = 2048; N = 2048; bx = (tb-1536) & 31;  by = (tb-1536) >> 5; }
  const int k0 = by*64, n0 = bx*64;
  #pragma unroll
  for (int ii = 0; ii < 16; ++ii) {
    int idx = ii*256 + t; int r = idx>>6, c = idx&63;
    ts[r][c] = W[(size_t)(k0+r)*N + n0 + c];
  }
  __syncthreads();
  // vectorized permuted store: 4 logical k-cols (one quad) -> contiguous short4v
  #pragma unroll
  for (int ii = 0; ii < 4; ++ii) {
    int idx = ii*256 + t;
    int r = idx >> 4;                 // n-row 0..63
    int q = idx & 15;                 // k-quad 0..15
    int c = q << 2;                   // logical k base
    int pcb = ((q & 8) << 2) | ((q & 3) << 3) | (q & 4);   // permuted quad base
    short4v o;
    o[0] = f2bs(ts[c][r]);   o[1] = f2bs(ts[c+1][r]);
    o[2] = f2bs(ts[c+2][r]); o[3] = f2bs(ts[c+3][r]);
    *(short4v*)(Wt + (size_t)(n0+r)*K + k0 + pcb) = o;
  }
}

// ---------------- QKV GEMM, FUSED RMSNorm+RoPE epilogue, b128 frags ----------------
// Q-heads additionally scaled by SCALE2. Q/K written d-PERMUTED; V written
// DIRECTLY TRANSPOSED into Vt [kv][64 d][2048 s-perm] (vtrans kernel eliminated).
__global__ __launch_bounds__(256) void k_gemm_qkv(const bf16* __restrict__ A, const bf16* __restrict__ Bt,
                                                  const float* __restrict__ cosb, const float* __restrict__ sinb,
                                                  const float* __restrict__ qg, const float* __restrict__ kg,
                                                  bf16* __restrict__ Qb, bf16* __restrict__ Kb,
                                                  bf16* __restrict__ Vt, int K) {
  __shared__ bf16 Asm[3][128*32];
  __shared__ bf16 Bsm[3][128*32];
  const int t = threadIdx.x;
  const int lane = t & 63, w = t >> 6;
  const int wr = w >> 1, wc = w & 1;
  const int m0 = blockIdx.y*128, n0 = blockIdx.x*128;
  const int l15 = lane & 15;
  const int g16 = (lane >> 4) << 4;

  f32x4 acc[4][4];
  #pragma unroll
  for (int i = 0; i < 4; ++i)
    #pragma unroll
    for (int j = 0; j < 4; ++j) acc[i][j] = 0.f;

  const char* Ab = (const char*)A;
  const char* Bb = (const char*)Bt;
  const int off  = t*16;
  const int srow = off >> 6;
  const int scolb = (((off >> 4) & 3) ^ ((srow >> 1) & 3)) << 4;

  const size_t arow0 = (size_t)(m0+srow)*K, arow1 = (size_t)(m0+srow+64)*K;
  const size_t brow0 = (size_t)(n0+srow)*K, brow1 = (size_t)(n0+srow+64)*K;

#define STAGE(buf, kk)  do {                                          \
    gload16(Ab + (arow0 + (kk))*2 + scolb, (char*)Asm[buf] + off);    \
    gload16(Ab + (arow1 + (kk))*2 + scolb, (char*)Asm[buf] + off + 4096); \
    gload16(Bb + (brow0 + (kk))*2 + scolb, (char*)Bsm[buf] + off);    \
    gload16(Bb + (brow1 + (kk))*2 + scolb, (char*)Bsm[buf] + off + 4096); \
  } while (0)

  const int nsteps = K >> 5;
  STAGE(0, 0);
  STAGE(1, 32);

  for (int it = 0; it < nsteps; ++it) {
    const int kf = (it + 2) << 5;
    if (kf < K) {
      STAGE((it + 2) % 3, kf);
      asm volatile("s_waitcnt vmcnt(8)" ::: "memory");
    } else if (it + 1 < nsteps) {
      asm volatile("s_waitcnt vmcnt(4)" ::: "memory");
    } else {
      asm volatile("s_waitcnt vmcnt(0)" ::: "memory");
    }
    __builtin_amdgcn_s_barrier();
    __builtin_amdgcn_sched_barrier(0);

    const char* Ac = (const char*)Asm[it % 3];
    const char* Bc = (const char*)Bsm[it % 3];
    short8v a[4], b[4];
    #pragma unroll
    for (int i = 0; i < 4; ++i) {
      const int arow = wr*64 + i*16 + l15;
      a[i] = *(const short8v*)(Ac + arow*64 + (g16 ^ (((arow >> 1) & 3) << 4)));
      const int brow = wc*64 + i*16 + l15;
      b[i] = *(const short8v*)(Bc + brow*64 + (g16 ^ (((brow >> 1) & 3) << 4)));
    }
    #pragma unroll
    for (int i = 0; i < 4; ++i)
      #pragma unroll
      for (int j = 0; j < 4; ++j)
        acc[i][j] = MFMA16(a[i], b[j], acc[i][j]);
    __builtin_amdgcn_sched_barrier(0);
    __builtin_amdgcn_s_barrier();
  }
#undef STAGE

  // ---- fused epilogue ----
  const int hh = (n0 + wc*64) >> 6;            // head id 0..47 (wave-uniform)
  if (hh < 40) {
    // rmsnorm + rope, d-PERMUTED store
    float gam[4];
    const float* gp = (hh < 32) ? qg : kg;
    #pragma unroll
    for (int j = 0; j < 4; ++j) gam[j] = gp[j*16 + l15];
    if (hh < 32) {
      #pragma unroll
      for (int j = 0; j < 4; ++j) gam[j] *= SCALE2;   // fold softmax scale into Q
    }
    const int pbase = ((l15 >> 2) << 3) + (l15 & 3);   // d-perm base for this lane
    #pragma unroll
    for (int i = 0; i < 4; ++i) {
      #pragma unroll
      for (int rr = 0; rr < 4; ++rr) {
        const int row = m0 + wr*64 + i*16 + ((lane>>4)<<2) + rr;   // absolute s
        float v0 = acc[i][0][rr], v1 = acc[i][1][rr], v2 = acc[i][2][rr], v3 = acc[i][3][rr];
        float ss = v0*v0 + v1*v1 + v2*v2 + v3*v3;
        ss += __shfl_xor(ss, 1); ss += __shfl_xor(ss, 2);
        ss += __shfl_xor(ss, 4); ss += __shfl_xor(ss, 8);
        const float rms = rsqrtf(ss*(1.0f/64.0f) + 1e-6f);
        const float t0 = v0*rms*gam[0], t1 = v1*rms*gam[1];
        const float t2 = v2*rms*gam[2], t3 = v3*rms*gam[3];
        const float* cr = cosb + (size_t)row*64;
        const float* sr = sinb + (size_t)row*64;
        const float o0 = t0*cr[l15]      - t2*sr[l15];
        const float o1 = t1*cr[16+l15]   - t3*sr[16+l15];
        const float o2 = t2*cr[32+l15]   + t0*sr[32+l15];
        const float o3 = t3*cr[48+l15]   + t1*sr[48+l15];
        bf16* dst = (hh < 32) ? (Qb + ((size_t)hh*2048 + row)*64)
                              : (Kb + ((size_t)(hh-32)*2048 + row)*64);
        dst[pbase]          = __float2bfloat16(o0);
        dst[pbase + 4]      = __float2bfloat16(o1);
        dst[32 + pbase]     = __float2bfloat16(o2);
        dst[32 + pbase + 4] = __float2bfloat16(o3);
      }
    }
  } else {
    // V: direct transposed store into Vt [kv][d][s-perm]; the 4 rr-values of
    // each (i,j) form one contiguous permuted quad -> short4v store.
    bf16* dstT = Vt + (size_t)(hh-40)*64*2048;
    #pragma unroll
    for (int i = 0; i < 4; ++i) {
      const int s_log = m0 + wr*64 + i*16 + ((lane>>4)<<2);   // 4-aligned quad base
      const int a_  = (s_log >> 2) & 7;                        // quad idx in 32-group
      const int ps  = (s_log & ~31) + ((a_ & 3) << 3) + ((a_ >> 2) << 2);
      #pragma unroll
      for (int j = 0; j < 4; ++j) {
        const int d = j*16 + l15;
        short4v vv;
        vv[0] = f2bs(acc[i][j][0]); vv[1] = f2bs(acc[i][j][1]);
        vv[2] = f2bs(acc[i][j][2]); vv[3] = f2bs(acc[i][j][3]);
        *(short4v*)(dstT + (size_t)d*2048 + ps) = vv;
      }
    }
  }
}

// ---------------- out-proj GEMM: direct f32 store, b128 frags, depth-2 prefetch ----------------
__global__ __launch_bounds__(256) void k_gemm_out(const bf16* __restrict__ A, const bf16* __restrict__ Bt,
                                                  float* __restrict__ C, int M, int N, int K, int ldc) {
  __shared__ bf16 Asm[3][128*32];
  __shared__ bf16 Bsm[3][128*32];
  const int t = threadIdx.x;
  const int lane = t & 63, w = t >> 6;
  const int wr = w >> 1, wc = w & 1;
  const int m0 = blockIdx.y*128, n0 = blockIdx.x*128;
  const int l15 = lane & 15;
  const int g16 = (lane >> 4) << 4;

  f32x4 acc[4][4];
  #pragma unroll
  for (int i = 0; i < 4; ++i)
    #pragma unroll
    for (int j = 0; j < 4; ++j) acc[i][j] = 0.f;

  const char* Ab = (const char*)A;
  const char* Bb = (const char*)Bt;
  const int off  = t*16;
  const int srow = off >> 6;
  const int scolb = (((off >> 4) & 3) ^ ((srow >> 1) & 3)) << 4;

  const size_t arow0 = (size_t)(m0+srow)*K, arow1 = (size_t)(m0+srow+64)*K;
  const size_t brow0 = (size_t)(n0+srow)*K, brow1 = (size_t)(n0+srow+64)*K;

#define STAGE(buf, kk)  do {                                          \
    gload16(Ab + (arow0 + (kk))*2 + scolb, (char*)Asm[buf] + off);    \
    gload16(Ab + (arow1 + (kk))*2 + scolb, (char*)Asm[buf] + off + 4096); \
    gload16(Bb + (brow0 + (kk))*2 + scolb, (char*)Bsm[buf] + off);    \
    gload16(Bb + (brow1 + (kk))*2 + scolb, (char*)Bsm[buf] + off + 4096); \
  } while (0)

  const int nsteps = K >> 5;
  STAGE(0, 0);
  STAGE(1, 32);

  for (int it = 0; it < nsteps; ++it) {
    if (it + 2 < nsteps) {
      STAGE((it + 2) % 3, (it + 2) << 5);
      asm volatile("s_waitcnt vmcnt(8)" ::: "memory");
    } else if (it + 1 < nsteps) {
      asm volatile("s_waitcnt vmcnt(4)" ::: "memory");
    } else {
      asm volatile("s_waitcnt vmcnt(0)" ::: "memory");
    }
    __builtin_amdgcn_s_barrier();
    __builtin_amdgcn_sched_barrier(0);

    const char* Ac = (const char*)Asm[it % 3];
    const char* Bc = (const char*)Bsm[it % 3];
    short8v a[4], b[4];
    #pragma unroll
    for (int i = 0; i < 4; ++i) {
      const int arow = wr*64 + i*16 + l15;
      a[i] = *(const short8v*)(Ac + arow*64 + (g16 ^ (((arow >> 1) & 3) << 4)));
      const int brow = wc*64 + i*16 + l15;
      b[i] = *(const short8v*)(Bc + brow*64 + (g16 ^ (((brow >> 1) & 3) << 4)));
    }
    #pragma unroll
    for (int i = 0; i < 4; ++i)
      #pragma unroll
      for (int j = 0; j < 4; ++j)
        acc[i][j] = MFMA16(a[i], b[j], acc[i][j]);
    __builtin_amdgcn_sched_barrier(0);
    __builtin_amdgcn_s_barrier();
  }
#undef STAGE

  #pragma unroll
  for (int i = 0; i < 4; ++i) {
    int row0 = m0 + wr*64 + i*16 + ((lane>>4)<<2);
    #pragma unroll
    for (int j = 0; j < 4; ++j) {
      int col = n0 + wc*64 + j*16 + l15;
      #pragma unroll
      for (int r = 0; r < 4; ++r)
        C[(size_t)(row0+r)*ldc + col] = acc[i][j][r];
    }
  }
}

// ---------------- causal flash attention v8: b128 frags + XOR-swizzled LDS (0-conflict) ----------------
// Linear rows + chunk-XOR swizzle (the QKV-GEMM-proven, measured-0-conflict scheme).
// Ksm [128][64]: chunk' = chunk ^ (row&7); Vsm [64][128]: chunk' = chunk ^ (row&15).
// Both write and read sides apply the same XOR (plain LDS stores -> rule 21 trivial).
__global__ __launch_bounds__(512) void k_attn(const bf16* __restrict__ Qb, const bf16* __restrict__ Kb,
                                              const bf16* __restrict__ Vt, bf16* __restrict__ attnb) {
  __shared__ __align__(1024) bf16 Ksm[128*64];
  __shared__ __align__(1024) bf16 Vsm[64*128];
  const int t = threadIdx.x, lane = t & 63, w = t >> 6;
  const int bid = blockIdx.x;
  const int h = bid & 31;
  const int qi = 15 - (bid >> 5);          // heavy blocks first
  const int qb0 = qi * 128;
  const int kvh = h >> 2;
  const int kb = (lane>>4)*4;
  const int kb2 = kb << 1;                 // permuted-contiguous frag base (8g)
  const int g = lane >> 4;                 // 16-lane group 0..3
  const int l15 = lane & 15;

  const bf16* Qh = Qb + (size_t)h*2048*64;
  const bf16* Kh = Kb + (size_t)kvh*2048*64;
  const bf16* Vh = Vt + (size_t)kvh*64*2048;

  const int qrow = qb0 + w*16 + l15;       // this lane's q-row (replicated x4 groups)
  short8v qf[2];
  #pragma unroll
  for (int kk = 0; kk < 2; ++kk)
    qf[kk] = *(const short8v*)(Qh + (size_t)qrow*64 + kk*32 + kb2);

  float m_ = -3e38f, ls = 0.f;
  f32x4 o2[4];
  #pragma unroll
  for (int j = 0; j < 4; ++j) o2[j] = 0.f;

  const int nt = qi + 1;
  for (int tt = 0; tt < nt; ++tt) {
    #pragma unroll
    for (int ii = 0; ii < 2; ++ii) {
      int idx = ii*512 + t;
      int kr = idx >> 3, kch = idx & 7;
      *(int4*)((char*)Ksm + kr*128 + ((kch ^ (kr & 7)) << 4)) =
          *(const int4*)(Kh + ((size_t)(tt*128 + kr))*64 + kch*8);
      int vr = idx >> 4, vch = idx & 15;
      *(int4*)((char*)Vsm + vr*256 + ((vch ^ (vr & 15)) << 4)) =
          *(const int4*)(Vh + (size_t)vr*2048 + tt*128 + vch*8);
    }
    __syncthreads();

    // S^T = K Q^T -> sAcc[j]: kv-block j (0..7), q = l15 (pre-scaled via Q)
    f32x4 sAcc[8];
    #pragma unroll
    for (int j = 0; j < 8; ++j) sAcc[j] = 0.f;
    __builtin_amdgcn_s_setprio(1);
    #pragma unroll
    for (int kk = 0; kk < 2; ++kk) {
      #pragma unroll
      for (int j = 0; j < 8; ++j) {
        const int row = j*16 + l15;
        short8v ak = *(const short8v*)((const char*)Ksm + row*128 +
                                       (((kk*4 + g) ^ (row & 7)) << 4));
        sAcc[j] = MFMA16(ak, qf[kk], sAcc[j]);
      }
    }
    __builtin_amdgcn_s_setprio(0);

    float p[8][4];
    #pragma unroll
    for (int j = 0; j < 8; ++j)
      #pragma unroll
      for (int r = 0; r < 4; ++r) p[j][r] = sAcc[j][r];
    if (tt == nt - 1) {                      // diagonal tile: causal mask
      #pragma unroll
      for (int j = 0; j < 8; ++j) {
        #pragma unroll
        for (int r = 0; r < 4; ++r)
          if (tt*128 + j*16 + kb + r > qrow) p[j][r] = -3e38f;
      }
    }

    // row max: max3 tree + cross-group combine
    float mj[8];
    #pragma unroll
    for (int j = 0; j < 8; ++j)
      mj[j] = fmaxf(max3f(p[j][0], p[j][1], p[j][2]), p[j][3]);
    float mx = fmaxf(max3f(mj[0], mj[1], mj[2]), max3f(mj[3], mj[4], mj[5]));
    mx = max3f(mx, mj[6], mj[7]);
    mx = fmaxf(mx, __shfl_xor(mx, 16));
    mx = fmaxf(mx, __shfl_xor(mx, 32));

    // defer-max (T13): skip rescale when tile max within 8 of running max
    float mn = m_;
    if (!__all(mx <= m_ + 8.f)) {
      mn = fmaxf(m_, mx);
      float alpha = exp2f(m_ - mn);
      m_ = mn;
      ls *= alpha;
      #pragma unroll
      for (int j = 0; j < 4; ++j) o2[j] *= alpha;
    }

    float rs = 0.f;
    #pragma unroll
    for (int j = 0; j < 8; ++j)
      #pragma unroll
      for (int r = 0; r < 4; ++r) {
        float e = exp2f(p[j][r] - mn);
        p[j][r] = e;
        rs += e;
      }
    rs += __shfl_xor(rs, 16);
    rs += __shfl_xor(rs, 32);
    ls += rs;

    short8v pb[4];
    #pragma unroll
    for (int kk = 0; kk < 4; ++kk) {
      short8v v;
      v[0] = f2bs(p[2*kk][0]);   v[1] = f2bs(p[2*kk][1]);
      v[2] = f2bs(p[2*kk][2]);   v[3] = f2bs(p[2*kk][3]);
      v[4] = f2bs(p[2*kk+1][0]); v[5] = f2bs(p[2*kk+1][1]);
      v[6] = f2bs(p[2*kk+1][2]); v[7] = f2bs(p[2*kk+1][3]);
      pb[kk] = v;
    }

    // O^T += V^T P -> o2[j]: d-block j, q = l15 (V kv-permuted -> b128 frags)
    __builtin_amdgcn_s_setprio(1);
    #pragma unroll
    for (int kk = 0; kk < 4; ++kk) {
      #pragma unroll
      for (int j = 0; j < 4; ++j) {
        const int row = j*16 + l15;
        short8v av = *(const short8v*)((const char*)Vsm + row*256 +
                                       (((kk*4 + g) ^ (row & 15)) << 4));
        o2[j] = MFMA16(av, pb[kk], o2[j]);
      }
    }
    __builtin_amdgcn_s_setprio(0);
    __syncthreads();
  }

  // write attnb in K-PERMUTED layout (out-proj A-operand)
  float inv = 1.0f / ls;
  #pragma unroll
  for (int j = 0; j < 4; ++j) {
    short4v vv;
    vv[0] = f2bs(o2[j][0]*inv); vv[1] = f2bs(o2[j][1]*inv);
    vv[2] = f2bs(o2[j][2]*inv); vv[3] = f2bs(o2[j][3]*inv);
    *(short4v*)(attnb + (size_t)qrow*2048 + h*64 + (j>>1)*32 + (kb<<1) + ((j&1)<<2)) = vv;
  }
}

extern "C" void kernel_launch(void* const* d_in, const int* in_sizes, int n_in,
                              void* d_out, int out_size, void* d_ws, size_t ws_size,
                              hipStream_t stream) {
  const float* x    = (const float*)d_in[0];
  const float* cosb = (const float*)d_in[2];
  const float* sinb = (const float*)d_in[3];
  const float* Wq   = (const float*)d_in[4];
  const float* Wk   = (const float*)d_in[5];
  const float* Wv   = (const float*)d_in[6];
  const float* Wo   = (const float*)d_in[7];
  const float* qg   = (const float*)d_in[8];
  const float* kg   = (const float*)d_in[9];
  float* out = (float*)d_out;

  char* ws = (char*)d_ws;
  bf16*  xb    = (bf16*)(ws);                    // 8 MB  K-perm (live thru QKV GEMM)
  bf16*  WqT   = (bf16*)(ws + 8388608);          // 8 MB  K-perm
  bf16*  WkT   = (bf16*)(ws + 16777216);         // 2 MB  K-perm
  bf16*  WvT   = (bf16*)(ws + 18874368);         // 2 MB  K-perm (contiguous N=3072 B-panel)
  bf16*  WoT   = (bf16*)(ws + 20971520);         // 8 MB  K-perm (live until out-proj)
  bf16*  Qb    = (bf16*)(ws + 29360128);         // 8 MB  [32][2048][64] d-perm, x SCALE2
  bf16*  Kb    = (bf16*)(ws + 37748736);         // 2 MB  [8][2048][64] d-perm
  bf16*  Vt    = (bf16*)(ws + 41943040);         // 2 MB  [8][64][2048] kv-perm cols (direct)
  bf16*  attnb = (bf16*)(ws);                    // 8 MB  K-perm (overlays dead xb)

  k_prep<<<6656, 256, 0, stream>>>(x, Wq, Wk, Wv, Wo, xb, WqT, WkT, WvT, WoT);
  k_gemm_qkv<<<dim3(24, 16), 256, 0, stream>>>(xb, WqT, cosb, sinb, qg, kg, Qb, Kb, Vt, 2048);
  k_attn<<<512, 512, 0, stream>>>(Qb, Kb, Vt, attnb);
  k_gemm_out<<<dim3(16, 16), 256, 0, stream>>>(attnb, WoT, out, 2048, 2048, 2048, 2048);
}

// Round 19
// 156.253 us; speedup vs baseline: 1.1416x; 1.0113x over previous
//
#include <hip/hip_runtime.h>
#include <hip/hip_bf16.h>
#include <stdint.h>

typedef __hip_bfloat16 bf16;
typedef __attribute__((ext_vector_type(4))) short short4v;
typedef __attribute__((ext_vector_type(8))) short short8v;
typedef __attribute__((ext_vector_type(4))) float f32x4;

#define MFMA16(a,b,c) __builtin_amdgcn_mfma_f32_16x16x32_bf16(a,b,c,0,0,0)
#define SCALE2 0.18033688011f   /* (1/sqrt(64)) * log2(e) — folded into Qb */

__device__ __forceinline__ void gload16(const void* g, void* l) {
  __builtin_amdgcn_global_load_lds((const __attribute__((address_space(1))) unsigned int*)g,
                                   (__attribute__((address_space(3))) unsigned int*)l, 16, 0, 0);
}

__device__ __forceinline__ short f2bs(float f) {
  return __builtin_bit_cast(short, __float2bfloat16(f));
}

__device__ __forceinline__ float max3f(float a, float b, float c) {
  return fmaxf(fmaxf(a, b), c);      // clang fuses to v_max3_f32 (T17)
}

// K-dim permutation within each 32-group: lane-group g's MFMA fragment
// {4g..4g+3, 16+4g..16+4g+3} becomes 8 CONTIGUOUS elements at 8g..8g+7.
// p(k) = ((k&15)>>2)*8 + ((k>>4)&1)*4 + (k&3)
// Applied to GEMM K-dims (xb/W*/attnb), attn d-dim (Qb/Kb), attn kv-dim (Vt cols).

// ---------------- merged prelude: cvt_x (permuted) + 4 transpose_cvt (permuted, b64 stores) ----------------
__global__ __launch_bounds__(256) void k_prep(const float* __restrict__ x,
    const float* __restrict__ Wq, const float* __restrict__ Wk,
    const float* __restrict__ Wv, const float* __restrict__ Wo,
    bf16* __restrict__ xb, bf16* __restrict__ WqT, bf16* __restrict__ WkT,
    bf16* __restrict__ WvT, bf16* __restrict__ WoT) {
  __shared__ float ts[64][65];
  const int bid = blockIdx.x;
  const int t = threadIdx.x;
  if (bid < 4096) {
    int f = (bid*256 + t)*4;
    int row = f >> 11, c = f & 2047;
    float4 v = *(const float4*)(x + (size_t)row*2048 + c);
    int pc = (c & ~31) | (((c & 15) >> 2) << 3) | (((c >> 4) & 1) << 2);
    short4v o;
    o[0] = f2bs(v.x); o[1] = f2bs(v.y); o[2] = f2bs(v.z); o[3] = f2bs(v.w);
    *(short4v*)(xb + (size_t)row*2048 + pc) = o;
    return;
  }
  int tb = bid - 4096;
  const float* W; bf16* Wt; int K, N, bx, by;
  if (tb < 1024)      { W = Wq; Wt = WqT; K = 2048; N = 2048; bx = tb & 31;         by = tb >> 5; }
  else if (tb < 1280) { W = Wk; Wt = WkT; K = 2048; N = 512;  bx = (tb-1024) & 7;   by = (tb-1024) >> 3; }
  else if (tb < 1536) { W = Wv; Wt = WvT; K = 2048; N = 512;  bx = (tb-1280) & 7;   by = (tb-1280) >> 3; }
  else                { W = Wo; Wt = WoT; K = 2048; N = 2048; bx = (tb-1536) & 31;  by = (tb-1536) >> 5; }
  const int k0 = by*64, n0 = bx*64;
  #pragma unroll
  for (int ii = 0; ii < 16; ++ii) {
    int idx = ii*256 + t; int r = idx>>6, c = idx&63;
    ts[r][c] = W[(size_t)(k0+r)*N + n0 + c];
  }
  __syncthreads();
  // vectorized permuted store: 4 logical k-cols (one quad) -> contiguous short4v
  #pragma unroll
  for (int ii = 0; ii < 4; ++ii) {
    int idx = ii*256 + t;
    int r = idx >> 4;                 // n-row 0..63
    int q = idx & 15;                 // k-quad 0..15
    int c = q << 2;                   // logical k base
    int pcb = ((q & 8) << 2) | ((q & 3) << 3) | (q & 4);   // permuted quad base
    short4v o;
    o[0] = f2bs(ts[c][r]);   o[1] = f2bs(ts[c+1][r]);
    o[2] = f2bs(ts[c+2][r]); o[3] = f2bs(ts[c+3][r]);
    *(short4v*)(Wt + (size_t)(n0+r)*K + k0 + pcb) = o;
  }
}

// ---------------- QKV GEMM, FUSED RMSNorm+RoPE epilogue, b128 frags, XCD swizzle ----------------
__global__ __launch_bounds__(256) void k_gemm_qkv(const bf16* __restrict__ A, const bf16* __restrict__ Bt,
                                                  const float* __restrict__ cosb, const float* __restrict__ sinb,
                                                  const float* __restrict__ qg, const float* __restrict__ kg,
                                                  bf16* __restrict__ Qb, bf16* __restrict__ Kb,
                                                  bf16* __restrict__ Vt, int K) {
  __shared__ bf16 Asm[3][128*32];
  __shared__ bf16 Bsm[3][128*32];
  const int t = threadIdx.x;
  const int lane = t & 63, w = t >> 6;
  const int wr = w >> 1, wc = w & 1;
  // XCD-chunked bijective block swizzle (nwg = 24*16 = 384, %8 == 0)
  const int nwg = gridDim.x * gridDim.y;
  int bid = blockIdx.y * gridDim.x + blockIdx.x;
  bid = (bid & 7) * (nwg >> 3) + (bid >> 3);
  const int m0 = (bid / gridDim.x) * 128;
  const int n0 = (bid % gridDim.x) * 128;
  const int l15 = lane & 15;
  const int g16 = (lane >> 4) << 4;

  f32x4 acc[4][4];
  #pragma unroll
  for (int i = 0; i < 4; ++i)
    #pragma unroll
    for (int j = 0; j < 4; ++j) acc[i][j] = 0.f;

  const char* Ab = (const char*)A;
  const char* Bb = (const char*)Bt;
  const int off  = t*16;
  const int srow = off >> 6;
  const int scolb = (((off >> 4) & 3) ^ ((srow >> 1) & 3)) << 4;

  const size_t arow0 = (size_t)(m0+srow)*K, arow1 = (size_t)(m0+srow+64)*K;
  const size_t brow0 = (size_t)(n0+srow)*K, brow1 = (size_t)(n0+srow+64)*K;

#define STAGE(buf, kk)  do {                                          \
    gload16(Ab + (arow0 + (kk))*2 + scolb, (char*)Asm[buf] + off);    \
    gload16(Ab + (arow1 + (kk))*2 + scolb, (char*)Asm[buf] + off + 4096); \
    gload16(Bb + (brow0 + (kk))*2 + scolb, (char*)Bsm[buf] + off);    \
    gload16(Bb + (brow1 + (kk))*2 + scolb, (char*)Bsm[buf] + off + 4096); \
  } while (0)

  const int nsteps = K >> 5;
  STAGE(0, 0);
  STAGE(1, 32);

  for (int it = 0; it < nsteps; ++it) {
    const int kf = (it + 2) << 5;
    if (kf < K) {
      STAGE((it + 2) % 3, kf);
      asm volatile("s_waitcnt vmcnt(8)" ::: "memory");
    } else if (it + 1 < nsteps) {
      asm volatile("s_waitcnt vmcnt(4)" ::: "memory");
    } else {
      asm volatile("s_waitcnt vmcnt(0)" ::: "memory");
    }
    __builtin_amdgcn_s_barrier();
    __builtin_amdgcn_sched_barrier(0);

    const char* Ac = (const char*)Asm[it % 3];
    const char* Bc = (const char*)Bsm[it % 3];
    short8v a[4], b[4];
    #pragma unroll
    for (int i = 0; i < 4; ++i) {
      const int arow = wr*64 + i*16 + l15;
      a[i] = *(const short8v*)(Ac + arow*64 + (g16 ^ (((arow >> 1) & 3) << 4)));
      const int brow = wc*64 + i*16 + l15;
      b[i] = *(const short8v*)(Bc + brow*64 + (g16 ^ (((brow >> 1) & 3) << 4)));
    }
    #pragma unroll
    for (int i = 0; i < 4; ++i)
      #pragma unroll
      for (int j = 0; j < 4; ++j)
        acc[i][j] = MFMA16(a[i], b[j], acc[i][j]);
    __builtin_amdgcn_sched_barrier(0);
    __builtin_amdgcn_s_barrier();
  }
#undef STAGE

  // ---- fused epilogue ----
  const int hh = (n0 + wc*64) >> 6;            // head id 0..47 (wave-uniform)
  if (hh < 40) {
    // rmsnorm + rope, d-PERMUTED store
    float gam[4];
    const float* gp = (hh < 32) ? qg : kg;
    #pragma unroll
    for (int j = 0; j < 4; ++j) gam[j] = gp[j*16 + l15];
    if (hh < 32) {
      #pragma unroll
      for (int j = 0; j < 4; ++j) gam[j] *= SCALE2;   // fold softmax scale into Q
    }
    const int pbase = ((l15 >> 2) << 3) + (l15 & 3);   // d-perm base for this lane
    #pragma unroll
    for (int i = 0; i < 4; ++i) {
      #pragma unroll
      for (int rr = 0; rr < 4; ++rr) {
        const int row = m0 + wr*64 + i*16 + ((lane>>4)<<2) + rr;   // absolute s
        float v0 = acc[i][0][rr], v1 = acc[i][1][rr], v2 = acc[i][2][rr], v3 = acc[i][3][rr];
        float ss = v0*v0 + v1*v1 + v2*v2 + v3*v3;
        ss += __shfl_xor(ss, 1); ss += __shfl_xor(ss, 2);
        ss += __shfl_xor(ss, 4); ss += __shfl_xor(ss, 8);
        const float rms = rsqrtf(ss*(1.0f/64.0f) + 1e-6f);
        const float t0 = v0*rms*gam[0], t1 = v1*rms*gam[1];
        const float t2 = v2*rms*gam[2], t3 = v3*rms*gam[3];
        const float* cr = cosb + (size_t)row*64;
        const float* sr = sinb + (size_t)row*64;
        const float o0 = t0*cr[l15]      - t2*sr[l15];
        const float o1 = t1*cr[16+l15]   - t3*sr[16+l15];
        const float o2 = t2*cr[32+l15]   + t0*sr[32+l15];
        const float o3 = t3*cr[48+l15]   + t1*sr[48+l15];
        bf16* dst = (hh < 32) ? (Qb + ((size_t)hh*2048 + row)*64)
                              : (Kb + ((size_t)(hh-32)*2048 + row)*64);
        dst[pbase]          = __float2bfloat16(o0);
        dst[pbase + 4]      = __float2bfloat16(o1);
        dst[32 + pbase]     = __float2bfloat16(o2);
        dst[32 + pbase + 4] = __float2bfloat16(o3);
      }
    }
  } else {
    // V: direct transposed store into Vt [kv][d][s-perm]; contiguous permuted quads.
    bf16* dstT = Vt + (size_t)(hh-40)*64*2048;
    #pragma unroll
    for (int i = 0; i < 4; ++i) {
      const int s_log = m0 + wr*64 + i*16 + ((lane>>4)<<2);   // 4-aligned quad base
      const int a_  = (s_log >> 2) & 7;                        // quad idx in 32-group
      const int ps  = (s_log & ~31) + ((a_ & 3) << 3) + ((a_ >> 2) << 2);
      #pragma unroll
      for (int j = 0; j < 4; ++j) {
        const int d = j*16 + l15;
        short4v vv;
        vv[0] = f2bs(acc[i][j][0]); vv[1] = f2bs(acc[i][j][1]);
        vv[2] = f2bs(acc[i][j][2]); vv[3] = f2bs(acc[i][j][3]);
        *(short4v*)(dstT + (size_t)d*2048 + ps) = vv;
      }
    }
  }
}

// ---------------- out-proj GEMM: direct f32 store, b128 frags, XCD swizzle ----------------
__global__ __launch_bounds__(256) void k_gemm_out(const bf16* __restrict__ A, const bf16* __restrict__ Bt,
                                                  float* __restrict__ C, int M, int N, int K, int ldc) {
  __shared__ bf16 Asm[3][128*32];
  __shared__ bf16 Bsm[3][128*32];
  const int t = threadIdx.x;
  const int lane = t & 63, w = t >> 6;
  const int wr = w >> 1, wc = w & 1;
  // XCD-chunked bijective block swizzle (nwg = 16*16 = 256, %8 == 0)
  const int nwg = gridDim.x * gridDim.y;
  int bid = blockIdx.y * gridDim.x + blockIdx.x;
  bid = (bid & 7) * (nwg >> 3) + (bid >> 3);
  const int m0 = (bid / gridDim.x) * 128;
  const int n0 = (bid % gridDim.x) * 128;
  const int l15 = lane & 15;
  const int g16 = (lane >> 4) << 4;

  f32x4 acc[4][4];
  #pragma unroll
  for (int i = 0; i < 4; ++i)
    #pragma unroll
    for (int j = 0; j < 4; ++j) acc[i][j] = 0.f;

  const char* Ab = (const char*)A;
  const char* Bb = (const char*)Bt;
  const int off  = t*16;
  const int srow = off >> 6;
  const int scolb = (((off >> 4) & 3) ^ ((srow >> 1) & 3)) << 4;

  const size_t arow0 = (size_t)(m0+srow)*K, arow1 = (size_t)(m0+srow+64)*K;
  const size_t brow0 = (size_t)(n0+srow)*K, brow1 = (size_t)(n0+srow+64)*K;

#define STAGE(buf, kk)  do {                                          \
    gload16(Ab + (arow0 + (kk))*2 + scolb, (char*)Asm[buf] + off);    \
    gload16(Ab + (arow1 + (kk))*2 + scolb, (char*)Asm[buf] + off + 4096); \
    gload16(Bb + (brow0 + (kk))*2 + scolb, (char*)Bsm[buf] + off);    \
    gload16(Bb + (brow1 + (kk))*2 + scolb, (char*)Bsm[buf] + off + 4096); \
  } while (0)

  const int nsteps = K >> 5;
  STAGE(0, 0);
  STAGE(1, 32);

  for (int it = 0; it < nsteps; ++it) {
    if (it + 2 < nsteps) {
      STAGE((it + 2) % 3, (it + 2) << 5);
      asm volatile("s_waitcnt vmcnt(8)" ::: "memory");
    } else if (it + 1 < nsteps) {
      asm volatile("s_waitcnt vmcnt(4)" ::: "memory");
    } else {
      asm volatile("s_waitcnt vmcnt(0)" ::: "memory");
    }
    __builtin_amdgcn_s_barrier();
    __builtin_amdgcn_sched_barrier(0);

    const char* Ac = (const char*)Asm[it % 3];
    const char* Bc = (const char*)Bsm[it % 3];
    short8v a[4], b[4];
    #pragma unroll
    for (int i = 0; i < 4; ++i) {
      const int arow = wr*64 + i*16 + l15;
      a[i] = *(const short8v*)(Ac + arow*64 + (g16 ^ (((arow >> 1) & 3) << 4)));
      const int brow = wc*64 + i*16 + l15;
      b[i] = *(const short8v*)(Bc + brow*64 + (g16 ^ (((brow >> 1) & 3) << 4)));
    }
    #pragma unroll
    for (int i = 0; i < 4; ++i)
      #pragma unroll
      for (int j = 0; j < 4; ++j)
        acc[i][j] = MFMA16(a[i], b[j], acc[i][j]);
    __builtin_amdgcn_sched_barrier(0);
    __builtin_amdgcn_s_barrier();
  }
#undef STAGE

  #pragma unroll
  for (int i = 0; i < 4; ++i) {
    int row0 = m0 + wr*64 + i*16 + ((lane>>4)<<2);
    #pragma unroll
    for (int j = 0; j < 4; ++j) {
      int col = n0 + wc*64 + j*16 + l15;
      #pragma unroll
      for (int r = 0; r < 4; ++r)
        C[(size_t)(row0+r)*ldc + col] = acc[i][j][r];
    }
  }
}

// ---------------- causal flash attention v8: b128 frags + XOR-swizzled LDS (0-conflict) ----------------
__global__ __launch_bounds__(512) void k_attn(const bf16* __restrict__ Qb, const bf16* __restrict__ Kb,
                                              const bf16* __restrict__ Vt, bf16* __restrict__ attnb) {
  __shared__ __align__(1024) bf16 Ksm[128*64];
  __shared__ __align__(1024) bf16 Vsm[64*128];
  const int t = threadIdx.x, lane = t & 63, w = t >> 6;
  const int bid = blockIdx.x;
  const int h = bid & 31;
  const int qi = 15 - (bid >> 5);          // heavy blocks first
  const int qb0 = qi * 128;
  const int kvh = h >> 2;
  const int kb = (lane>>4)*4;
  const int kb2 = kb << 1;                 // permuted-contiguous frag base (8g)
  const int g = lane >> 4;                 // 16-lane group 0..3
  const int l15 = lane & 15;

  const bf16* Qh = Qb + (size_t)h*2048*64;
  const bf16* Kh = Kb + (size_t)kvh*2048*64;
  const bf16* Vh = Vt + (size_t)kvh*64*2048;

  const int qrow = qb0 + w*16 + l15;       // this lane's q-row (replicated x4 groups)
  short8v qf[2];
  #pragma unroll
  for (int kk = 0; kk < 2; ++kk)
    qf[kk] = *(const short8v*)(Qh + (size_t)qrow*64 + kk*32 + kb2);

  float m_ = -3e38f, ls = 0.f;
  f32x4 o2[4];
  #pragma unroll
  for (int j = 0; j < 4; ++j) o2[j] = 0.f;

  const int nt = qi + 1;
  for (int tt = 0; tt < nt; ++tt) {
    #pragma unroll
    for (int ii = 0; ii < 2; ++ii) {
      int idx = ii*512 + t;
      int kr = idx >> 3, kch = idx & 7;
      *(int4*)((char*)Ksm + kr*128 + ((kch ^ (kr & 7)) << 4)) =
          *(const int4*)(Kh + ((size_t)(tt*128 + kr))*64 + kch*8);
      int vr = idx >> 4, vch = idx & 15;
      *(int4*)((char*)Vsm + vr*256 + ((vch ^ (vr & 15)) << 4)) =
          *(const int4*)(Vh + (size_t)vr*2048 + tt*128 + vch*8);
    }
    __syncthreads();

    // S^T = K Q^T -> sAcc[j]: kv-block j (0..7), q = l15 (pre-scaled via Q)
    f32x4 sAcc[8];
    #pragma unroll
    for (int j = 0; j < 8; ++j) sAcc[j] = 0.f;
    __builtin_amdgcn_s_setprio(1);
    #pragma unroll
    for (int kk = 0; kk < 2; ++kk) {
      #pragma unroll
      for (int j = 0; j < 8; ++j) {
        const int row = j*16 + l15;
        short8v ak = *(const short8v*)((const char*)Ksm + row*128 +
                                       (((kk*4 + g) ^ (row & 7)) << 4));
        sAcc[j] = MFMA16(ak, qf[kk], sAcc[j]);
      }
    }
    __builtin_amdgcn_s_setprio(0);

    float p[8][4];
    #pragma unroll
    for (int j = 0; j < 8; ++j)
      #pragma unroll
      for (int r = 0; r < 4; ++r) p[j][r] = sAcc[j][r];
    if (tt == nt - 1) {                      // diagonal tile: causal mask
      #pragma unroll
      for (int j = 0; j < 8; ++j) {
        #pragma unroll
        for (int r = 0; r < 4; ++r)
          if (tt*128 + j*16 + kb + r > qrow) p[j][r] = -3e38f;
      }
    }

    // row max: max3 tree + cross-group combine
    float mj[8];
    #pragma unroll
    for (int j = 0; j < 8; ++j)
      mj[j] = fmaxf(max3f(p[j][0], p[j][1], p[j][2]), p[j][3]);
    float mx = fmaxf(max3f(mj[0], mj[1], mj[2]), max3f(mj[3], mj[4], mj[5]));
    mx = max3f(mx, mj[6], mj[7]);
    mx = fmaxf(mx, __shfl_xor(mx, 16));
    mx = fmaxf(mx, __shfl_xor(mx, 32));

    // defer-max (T13): skip rescale when tile max within 8 of running max
    float mn = m_;
    if (!__all(mx <= m_ + 8.f)) {
      mn = fmaxf(m_, mx);
      float alpha = exp2f(m_ - mn);
      m_ = mn;
      ls *= alpha;
      #pragma unroll
      for (int j = 0; j < 4; ++j) o2[j] *= alpha;
    }

    float rs = 0.f;
    #pragma unroll
    for (int j = 0; j < 8; ++j)
      #pragma unroll
      for (int r = 0; r < 4; ++r) {
        float e = exp2f(p[j][r] - mn);
        p[j][r] = e;
        rs += e;
      }
    rs += __shfl_xor(rs, 16);
    rs += __shfl_xor(rs, 32);
    ls += rs;

    short8v pb[4];
    #pragma unroll
    for (int kk = 0; kk < 4; ++kk) {
      short8v v;
      v[0] = f2bs(p[2*kk][0]);   v[1] = f2bs(p[2*kk][1]);
      v[2] = f2bs(p[2*kk][2]);   v[3] = f2bs(p[2*kk][3]);
      v[4] = f2bs(p[2*kk+1][0]); v[5] = f2bs(p[2*kk+1][1]);
      v[6] = f2bs(p[2*kk+1][2]); v[7] = f2bs(p[2*kk+1][3]);
      pb[kk] = v;
    }

    // O^T += V^T P -> o2[j]: d-block j, q = l15 (V kv-permuted -> b128 frags)
    __builtin_amdgcn_s_setprio(1);
    #pragma unroll
    for (int kk = 0; kk < 4; ++kk) {
      #pragma unroll
      for (int j = 0; j < 4; ++j) {
        const int row = j*16 + l15;
        short8v av = *(const short8v*)((const char*)Vsm + row*256 +
                                       (((kk*4 + g) ^ (row & 15)) << 4));
        o2[j] = MFMA16(av, pb[kk], o2[j]);
      }
    }
    __builtin_amdgcn_s_setprio(0);
    __syncthreads();
  }

  // write attnb in K-PERMUTED layout (out-proj A-operand)
  float inv = 1.0f / ls;
  #pragma unroll
  for (int j = 0; j < 4; ++j) {
    short4v vv;
    vv[0] = f2bs(o2[j][0]*inv); vv[1] = f2bs(o2[j][1]*inv);
    vv[2] = f2bs(o2[j][2]*inv); vv[3] = f2bs(o2[j][3]*inv);
    *(short4v*)(attnb + (size_t)qrow*2048 + h*64 + (j>>1)*32 + (kb<<1) + ((j&1)<<2)) = vv;
  }
}

extern "C" void kernel_launch(void* const* d_in, const int* in_sizes, int n_in,
                              void* d_out, int out_size, void* d_ws, size_t ws_size,
                              hipStream_t stream) {
  const float* x    = (const float*)d_in[0];
  const float* cosb = (const float*)d_in[2];
  const float* sinb = (const float*)d_in[3];
  const float* Wq   = (const float*)d_in[4];
  const float* Wk   = (const float*)d_in[5];
  const float* Wv   = (const float*)d_in[6];
  const float* Wo   = (const float*)d_in[7];
  const float* qg   = (const float*)d_in[8];
  const float* kg   = (const float*)d_in[9];
  float* out = (float*)d_out;

  char* ws = (char*)d_ws;
  bf16*  xb    = (bf16*)(ws);                    // 8 MB  K-perm (live thru QKV GEMM)
  bf16*  WqT   = (bf16*)(ws + 8388608);          // 8 MB  K-perm
  bf16*  WkT   = (bf16*)(ws + 16777216);         // 2 MB  K-perm
  bf16*  WvT   = (bf16*)(ws + 18874368);         // 2 MB  K-perm (contiguous N=3072 B-panel)
  bf16*  WoT   = (bf16*)(ws + 20971520);         // 8 MB  K-perm (live until out-proj)
  bf16*  Qb    = (bf16*)(ws + 29360128);         // 8 MB  [32][2048][64] d-perm, x SCALE2
  bf16*  Kb    = (bf16*)(ws + 37748736);         // 2 MB  [8][2048][64] d-perm
  bf16*  Vt    = (bf16*)(ws + 41943040);         // 2 MB  [8][64][2048] kv-perm cols (direct)
  bf16*  attnb = (bf16*)(ws);                    // 8 MB  K-perm (overlays dead xb)

  k_prep<<<6656, 256, 0, stream>>>(x, Wq, Wk, Wv, Wo, xb, WqT, WkT, WvT, WoT);
  k_gemm_qkv<<<dim3(24, 16), 256, 0, stream>>>(xb, WqT, cosb, sinb, qg, kg, Qb, Kb, Vt, 2048);
  k_attn<<<512, 512, 0, stream>>>(Qb, Kb, Vt, attnb);
  k_gemm_out<<<dim3(16, 16), 256, 0, stream>>>(attnb, WoT, out, 2048, 2048, 2048, 2048);
}